// Round 1
// baseline (644.603 us; speedup 1.0000x reference)
//
#include <hip/hip_runtime.h>
#include <hip/hip_bf16.h>
#include <stdint.h>

typedef __attribute__((ext_vector_type(4))) float f32x4;
typedef __attribute__((ext_vector_type(8))) short bf16x8;

#define SEQ 2048
#define HIDDEN 2880
#define NQ 64
#define NKV 8
#define HD 64
#define QKV_DIM 5120
#define Q_SZ 4096
#define K_SZ 512
#define OW_N 2880
#define OW_NPAD 2944
#define OW_K 4096

__device__ __forceinline__ unsigned short f2b_bits(float f) {
    unsigned int x = __float_as_uint(f);
    unsigned int r = (x + 0x7fffu + ((x >> 16) & 1u)) >> 16;  // RNE
    return (unsigned short)r;
}
__device__ __forceinline__ float b2f(unsigned short u) {
    return __uint_as_float(((unsigned int)u) << 16);
}

__device__ __forceinline__ void llds16(const ushort* g, ushort* l) {
    __builtin_amdgcn_global_load_lds(
        (const __attribute__((address_space(1))) void*)g,
        (__attribute__((address_space(3))) void*)l, 16, 0, 0);
}

// ---------------- fp32 -> bf16 conversion ----------------
__global__ void convert_f32(const float* __restrict__ in, ushort* __restrict__ out, int n4) {
    int i = blockIdx.x * blockDim.x + threadIdx.x;
    int stride = gridDim.x * blockDim.x;
    for (; i < n4; i += stride) {
        float4 v = reinterpret_cast<const float4*>(in)[i];
        ushort4 o = make_ushort4(f2b_bits(v.x), f2b_bits(v.y), f2b_bits(v.z), f2b_bits(v.w));
        reinterpret_cast<ushort4*>(out)[i] = o;
    }
}

// o_w [2880][4096] -> bf16 padded to [2944][4096] (pad rows zero)
__global__ void convert_ow(const float* __restrict__ in, ushort* __restrict__ out) {
    int i = blockIdx.x * blockDim.x + threadIdx.x;
    const int n4 = OW_NPAD * OW_K / 4;
    int stride = gridDim.x * blockDim.x;
    for (; i < n4; i += stride) {
        int row = (i * 4) >> 12;  // /4096
        ushort4 o;
        if (row < OW_N) {
            float4 v = reinterpret_cast<const float4*>(in)[i];
            o = make_ushort4(f2b_bits(v.x), f2b_bits(v.y), f2b_bits(v.z), f2b_bits(v.w));
        } else {
            o = make_ushort4(0, 0, 0, 0);
        }
        reinterpret_cast<ushort4*>(out)[i] = o;
    }
}

// ---------------- bf16 GEMM, B^T layout: C[m][n] = sum_k A[m][k]*B[n][k] + bias[n] ----------------
// 128x128 tile, BK=64, 4 waves (2x2), global_load_lds staging with XOR swizzle.
template<int OUT_BF16>
__global__ __launch_bounds__(256) void gemm_bt(
    const ushort* __restrict__ A, const ushort* __restrict__ B,
    const float* __restrict__ bias, void* __restrict__ Cout,
    int M, int N, int K, int Nreal, int ldC)
{
    __shared__ __align__(16) ushort As[128 * 64];
    __shared__ __align__(16) ushort Bs[128 * 64];
    const int tid = threadIdx.x;
    const int lane = tid & 63;
    const int w = tid >> 6;
    const int wr = w >> 1, wc = w & 1;
    const int m0 = blockIdx.y * 128, n0 = blockIdx.x * 128;

    f32x4 acc[4][4] = {};

    for (int k0 = 0; k0 < K; k0 += 64) {
        #pragma unroll
        for (int it = 0; it < 4; ++it) {
            int i = it * 256 + tid;              // physical 16B chunk index
            int row = i >> 3;
            int col16 = (i ^ (row & 7)) & 7;     // inverse-swizzled source column
            const ushort* ga = A + (size_t)(m0 + row) * K + k0 + col16 * 8;
            ushort* la = As + (size_t)(it * 256 + (tid & ~63)) * 8;  // wave-uniform dest
            llds16(ga, la);
            const ushort* gb = B + (size_t)(n0 + row) * K + k0 + col16 * 8;
            ushort* lb = Bs + (size_t)(it * 256 + (tid & ~63)) * 8;
            llds16(gb, lb);
        }
        __syncthreads();  // drains vmcnt before barrier
        #pragma unroll
        for (int kk = 0; kk < 2; ++kk) {
            bf16x8 a[4], b[4];
            #pragma unroll
            for (int mi = 0; mi < 4; ++mi) {
                int row = wr * 64 + mi * 16 + (lane & 15);
                int byte = row * 128 + kk * 64 + (lane >> 4) * 16;
                byte ^= (row & 7) << 4;
                a[mi] = *reinterpret_cast<const bf16x8*>(reinterpret_cast<const char*>(As) + byte);
            }
            #pragma unroll
            for (int ni = 0; ni < 4; ++ni) {
                int row = wc * 64 + ni * 16 + (lane & 15);
                int byte = row * 128 + kk * 64 + (lane >> 4) * 16;
                byte ^= (row & 7) << 4;
                b[ni] = *reinterpret_cast<const bf16x8*>(reinterpret_cast<const char*>(Bs) + byte);
            }
            #pragma unroll
            for (int mi = 0; mi < 4; ++mi)
                #pragma unroll
                for (int ni = 0; ni < 4; ++ni)
                    acc[mi][ni] = __builtin_amdgcn_mfma_f32_16x16x32_bf16(a[mi], b[ni], acc[mi][ni], 0, 0, 0);
        }
        __syncthreads();
    }

    #pragma unroll
    for (int mi = 0; mi < 4; ++mi) {
        int gr = m0 + wr * 64 + mi * 16 + (lane >> 4) * 4;
        #pragma unroll
        for (int ni = 0; ni < 4; ++ni) {
            int gc = n0 + wc * 64 + ni * 16 + (lane & 15);
            if (gc < Nreal) {
                float bv = bias[gc];
                #pragma unroll
                for (int r = 0; r < 4; ++r) {
                    float v = acc[mi][ni][r] + bv;
                    if (OUT_BF16)
                        ((ushort*)Cout)[(size_t)(gr + r) * ldC + gc] = f2b_bits(v);
                    else
                        ((float*)Cout)[(size_t)(gr + r) * ldC + gc] = v;
                }
            }
        }
    }
}

// ---------------- RoPE (YaRN) + split + q-prescale ----------------
__global__ __launch_bounds__(256) void rope_kernel(
    const ushort* __restrict__ qkv, const int* __restrict__ pos,
    ushort* __restrict__ q_ro, ushort* __restrict__ k_ro)
{
    __shared__ float cosv[32], sinv[32];
    const int s = blockIdx.x;
    const int tid = threadIdx.x;
    if (tid < 32) {
        int j = tid;
        const float logbase = logf(150000.0f);
        float freq = __expf((float)j * (logbase * (1.0f / 32.0f)) * 0.6931471805599453f / 0.6931471805599453f);
        // freq = BASE^(j/32) computed via expf for accuracy
        freq = expf((float)j * (logbase / 32.0f));
        float interp = 1.0f / (32.0f * freq);
        float extrap = 1.0f / freq;
        const float twopi = 6.283185307179586f;
        float low  = 32.0f * logf(4096.0f / (32.0f * twopi)) / logbase;
        float high = 32.0f * logf(4096.0f / (1.0f  * twopi)) / logbase;
        float ramp = ((float)j - low) / (high - low);
        float mask = 1.0f - fminf(fmaxf(ramp, 0.0f), 1.0f);
        float inv_freq = interp * (1.0f - mask) + extrap * mask;
        float ang = (float)pos[s] * inv_freq;
        const float conc = 0.1f * logf(32.0f) + 1.0f;
        cosv[j] = cosf(ang) * conc;
        sinv[j] = sinf(ang) * conc;
    }
    __syncthreads();
    // queries: 64 heads * 32 pairs = 2048, pre-scaled by HEAD_DIM^-0.5 = 0.125
    #pragma unroll
    for (int it = 0; it < 8; ++it) {
        int idx = it * 256 + tid;
        int h = idx >> 5, j = idx & 31;
        const ushort* src = qkv + (size_t)s * QKV_DIM + h * HD;
        float x1 = b2f(src[j]), x2 = b2f(src[j + 32]);
        float c = cosv[j], sn = sinv[j];
        ushort* dst = q_ro + ((size_t)h * SEQ + s) * HD;
        dst[j]      = f2b_bits((x1 * c - x2 * sn) * 0.125f);
        dst[j + 32] = f2b_bits((x2 * c + x1 * sn) * 0.125f);
    }
    // keys: 8 heads * 32 pairs = 256 (no scaling)
    {
        int h = tid >> 5, j = tid & 31;
        const ushort* src = qkv + (size_t)s * QKV_DIM + Q_SZ + h * HD;
        float x1 = b2f(src[j]), x2 = b2f(src[j + 32]);
        float c = cosv[j], sn = sinv[j];
        ushort* dst = k_ro + ((size_t)h * SEQ + s) * HD;
        dst[j]      = f2b_bits(x1 * c - x2 * sn);
        dst[j + 32] = f2b_bits(x2 * c + x1 * sn);
    }
}

// ---------------- V transpose: qkv[s][4608 + kh*64 + d] -> vT[kh][d][s] ----------------
__global__ __launch_bounds__(256) void vtrans_kernel(const ushort* __restrict__ qkv, ushort* __restrict__ vT) {
    __shared__ ushort t[64][65];
    const int kh = blockIdx.x >> 5;
    const int s0 = (blockIdx.x & 31) * 64;
    const int tid = threadIdx.x;
    #pragma unroll
    for (int it = 0; it < 16; ++it) {
        int e = it * 256 + tid;
        int sl = e >> 6, d = e & 63;
        t[d][sl] = qkv[(size_t)(s0 + sl) * QKV_DIM + Q_SZ + K_SZ + kh * HD + d];
    }
    __syncthreads();
    #pragma unroll
    for (int it = 0; it < 16; ++it) {
        int e = it * 256 + tid;
        int d = e >> 6, sl = e & 63;
        vT[((size_t)kh * HD + d) * SEQ + s0 + sl] = t[d][sl];
    }
}

// ---------------- attention: flash-style, sink, reverse sliding window ----------------
__global__ __launch_bounds__(256) void attn_kernel(
    const ushort* __restrict__ q_ro, const ushort* __restrict__ k_ro,
    const ushort* __restrict__ vT, const float* __restrict__ sinks,
    ushort* __restrict__ attn_out)
{
    __shared__ __align__(16) char Plds[4 * 2048];
    const int tid = threadIdx.x;
    const int lane = tid & 63;
    const int w = tid >> 6;
    const int h = blockIdx.x >> 5;
    const int q0 = (blockIdx.x & 31) * 64;
    const int kh = h >> 3;
    const int qw = q0 + w * 16;
    char* pbase = Plds + w * 2048;

    bf16x8 aq[2];
    {
        int row = qw + (lane & 15);
        const ushort* qp = q_ro + ((size_t)h * SEQ + row) * HD + (lane >> 4) * 8;
        aq[0] = *reinterpret_cast<const bf16x8*>(qp);
        aq[1] = *reinterpret_cast<const bf16x8*>(qp + 32);
    }
    float m[4], l[4];
    f32x4 o[4] = {};
    const float snk = sinks[h];
    #pragma unroll
    for (int r = 0; r < 4; ++r) { m[r] = snk; l[r] = 1.0f; }

    const int kt_start = (q0 >= 128) ? ((q0 - 128) >> 6) : 0;
    for (int kt = kt_start; kt < SEQ / 64; ++kt) {
        const int k0 = kt * 64;
        f32x4 s[4];
        const f32x4 z = {0.f, 0.f, 0.f, 0.f};
        __builtin_amdgcn_s_setprio(1);
        #pragma unroll
        for (int c = 0; c < 4; ++c) {
            int krow = k0 + c * 16 + (lane & 15);
            const ushort* kp = k_ro + ((size_t)kh * SEQ + krow) * HD + (lane >> 4) * 8;
            bf16x8 b0 = *reinterpret_cast<const bf16x8*>(kp);
            bf16x8 b1 = *reinterpret_cast<const bf16x8*>(kp + 32);
            s[c] = __builtin_amdgcn_mfma_f32_16x16x32_bf16(aq[0], b0, z, 0, 0, 0);
            s[c] = __builtin_amdgcn_mfma_f32_16x16x32_bf16(aq[1], b1, s[c], 0, 0, 0);
        }
        __builtin_amdgcn_s_setprio(0);
        if (k0 < q0 - 64) {  // only the first tile can contain masked pairs
            #pragma unroll
            for (int c = 0; c < 4; ++c) {
                int kg = k0 + c * 16 + (lane & 15);
                #pragma unroll
                for (int r = 0; r < 4; ++r) {
                    int qg = qw + (lane >> 4) * 4 + r;
                    if (qg - kg > 128) s[c][r] = -1e30f;
                }
            }
        }
        // online softmax (rows (lane>>4)*4+r live in 16-lane groups)
        float tmax[4], psum[4], p[4][4], sc[4];
        #pragma unroll
        for (int r = 0; r < 4; ++r)
            tmax[r] = fmaxf(fmaxf(s[0][r], s[1][r]), fmaxf(s[2][r], s[3][r]));
        #pragma unroll
        for (int d = 1; d <= 8; d <<= 1)
            #pragma unroll
            for (int r = 0; r < 4; ++r)
                tmax[r] = fmaxf(tmax[r], __shfl_xor(tmax[r], d));
        #pragma unroll
        for (int r = 0; r < 4; ++r) {
            float mn = fmaxf(m[r], tmax[r]);
            sc[r] = __expf(m[r] - mn);
            m[r] = mn;
        }
        #pragma unroll
        for (int c = 0; c < 4; ++c)
            #pragma unroll
            for (int r = 0; r < 4; ++r)
                p[c][r] = __expf(s[c][r] - m[r]);
        #pragma unroll
        for (int r = 0; r < 4; ++r)
            psum[r] = (p[0][r] + p[1][r]) + (p[2][r] + p[3][r]);
        #pragma unroll
        for (int d = 1; d <= 8; d <<= 1)
            #pragma unroll
            for (int r = 0; r < 4; ++r)
                psum[r] += __shfl_xor(psum[r], d);
        #pragma unroll
        for (int r = 0; r < 4; ++r)
            l[r] = l[r] * sc[r] + psum[r];
        #pragma unroll
        for (int i = 0; i < 4; ++i)
            #pragma unroll
            for (int r = 0; r < 4; ++r)
                o[i][r] *= sc[r];
        // P -> LDS (bf16, XOR-swizzled rows)
        #pragma unroll
        for (int c = 0; c < 4; ++c)
            #pragma unroll
            for (int r = 0; r < 4; ++r) {
                int row = (lane >> 4) * 4 + r;
                int col = c * 16 + (lane & 15);
                int byte = row * 128 + col * 2;
                byte ^= (row & 7) << 4;
                *reinterpret_cast<ushort*>(pbase + byte) = f2b_bits(p[c][r]);
            }
        // PV
        __builtin_amdgcn_s_setprio(1);
        #pragma unroll
        for (int kk = 0; kk < 2; ++kk) {
            int row = lane & 15;
            int byte = row * 128 + kk * 64 + (lane >> 4) * 16;
            byte ^= (row & 7) << 4;
            bf16x8 ap = *reinterpret_cast<const bf16x8*>(pbase + byte);
            #pragma unroll
            for (int i = 0; i < 4; ++i) {
                const ushort* vp = vT + ((size_t)kh * HD + i * 16 + (lane & 15)) * SEQ + k0 + kk * 32 + (lane >> 4) * 8;
                bf16x8 bv = *reinterpret_cast<const bf16x8*>(vp);
                o[i] = __builtin_amdgcn_mfma_f32_16x16x32_bf16(ap, bv, o[i], 0, 0, 0);
            }
        }
        __builtin_amdgcn_s_setprio(0);
    }
    #pragma unroll
    for (int i = 0; i < 4; ++i)
        #pragma unroll
        for (int r = 0; r < 4; ++r) {
            int row = qw + (lane >> 4) * 4 + r;
            int col = i * 16 + (lane & 15);
            float v = o[i][r] / l[r];
            attn_out[(size_t)row * Q_SZ + h * HD + col] = f2b_bits(v);
        }
}

extern "C" void kernel_launch(void* const* d_in, const int* in_sizes, int n_in,
                              void* d_out, int out_size, void* d_ws, size_t ws_size,
                              hipStream_t stream) {
    const float* hidden = (const float*)d_in[0];
    const float* qkv_w  = (const float*)d_in[1];
    const float* qkv_b  = (const float*)d_in[2];
    const float* o_w    = (const float*)d_in[3];
    const float* o_b    = (const float*)d_in[4];
    const float* sinks  = (const float*)d_in[5];
    const int*   pos    = (const int*)d_in[6];
    float* out = (float*)d_out;

    char* ws = (char*)d_ws;
    size_t off = 0;
    auto alloc = [&](size_t bytes) {
        char* p = ws + off;
        off += (bytes + 255) & ~(size_t)255;
        return p;
    };
    ushort* hs_bf   = (ushort*)alloc((size_t)SEQ * HIDDEN * 2);
    ushort* wqkv_bf = (ushort*)alloc((size_t)QKV_DIM * HIDDEN * 2);
    ushort* qkv_bf  = (ushort*)alloc((size_t)SEQ * QKV_DIM * 2);
    ushort* q_ro    = (ushort*)alloc((size_t)NQ * SEQ * HD * 2);
    ushort* k_ro    = (ushort*)alloc((size_t)NKV * SEQ * HD * 2);
    ushort* vT      = (ushort*)alloc((size_t)NKV * HD * SEQ * 2);
    ushort* attn_bf = (ushort*)alloc((size_t)SEQ * Q_SZ * 2);
    ushort* wo_bf   = (ushort*)alloc((size_t)OW_NPAD * OW_K * 2);

    convert_f32<<<2048, 256, 0, stream>>>(hidden, hs_bf, SEQ * HIDDEN / 4);
    convert_f32<<<2048, 256, 0, stream>>>(qkv_w, wqkv_bf, QKV_DIM * HIDDEN / 4);
    convert_ow<<<2048, 256, 0, stream>>>(o_w, wo_bf);

    gemm_bt<1><<<dim3(QKV_DIM / 128, SEQ / 128), 256, 0, stream>>>(
        hs_bf, wqkv_bf, qkv_b, qkv_bf, SEQ, QKV_DIM, HIDDEN, QKV_DIM, QKV_DIM);

    rope_kernel<<<SEQ, 256, 0, stream>>>(qkv_bf, pos, q_ro, k_ro);
    vtrans_kernel<<<NKV * 32, 256, 0, stream>>>(qkv_bf, vT);

    attn_kernel<<<NQ * 32, 256, 0, stream>>>(q_ro, k_ro, vT, sinks, attn_bf);

    gemm_bt<0><<<dim3(OW_NPAD / 128, SEQ / 128), 256, 0, stream>>>(
        attn_bf, wo_bf, o_b, out, SEQ, OW_NPAD, OW_K, OW_N, OW_N);
}

// Round 2
// 346.496 us; speedup vs baseline: 1.8603x; 1.8603x over previous
//
#include <hip/hip_runtime.h>
#include <hip/hip_bf16.h>
#include <stdint.h>

typedef __attribute__((ext_vector_type(4))) float f32x4;
typedef __attribute__((ext_vector_type(8))) short bf16x8;

#define SEQ 2048
#define HIDDEN 2880
#define NQ 64
#define NKV 8
#define HD 64
#define QKV_DIM 5120
#define Q_SZ 4096
#define K_SZ 512
#define OW_N 2880
#define OW_NPAD 2944
#define OW_K 4096

__device__ __forceinline__ unsigned short f2b_bits(float f) {
    unsigned int x = __float_as_uint(f);
    unsigned int r = (x + 0x7fffu + ((x >> 16) & 1u)) >> 16;  // RNE
    return (unsigned short)r;
}
__device__ __forceinline__ float b2f(unsigned short u) {
    return __uint_as_float(((unsigned int)u) << 16);
}

__device__ __forceinline__ void llds16(const ushort* g, ushort* l) {
    __builtin_amdgcn_global_load_lds(
        (const __attribute__((address_space(1))) void*)g,
        (__attribute__((address_space(3))) void*)l, 16, 0, 0);
}

// ---------------- fp32 -> bf16 conversion ----------------
__global__ void convert_f32(const float* __restrict__ in, ushort* __restrict__ out, int n4) {
    int i = blockIdx.x * blockDim.x + threadIdx.x;
    int stride = gridDim.x * blockDim.x;
    for (; i < n4; i += stride) {
        float4 v = reinterpret_cast<const float4*>(in)[i];
        ushort4 o = make_ushort4(f2b_bits(v.x), f2b_bits(v.y), f2b_bits(v.z), f2b_bits(v.w));
        reinterpret_cast<ushort4*>(out)[i] = o;
    }
}

// o_w [2880][4096] -> bf16 padded to [2944][4096] (pad rows zero)
__global__ void convert_ow(const float* __restrict__ in, ushort* __restrict__ out) {
    int i = blockIdx.x * blockDim.x + threadIdx.x;
    const int n4 = OW_NPAD * OW_K / 4;
    int stride = gridDim.x * blockDim.x;
    for (; i < n4; i += stride) {
        int row = (i * 4) >> 12;  // /4096
        ushort4 o;
        if (row < OW_N) {
            float4 v = reinterpret_cast<const float4*>(in)[i];
            o = make_ushort4(f2b_bits(v.x), f2b_bits(v.y), f2b_bits(v.z), f2b_bits(v.w));
        } else {
            o = make_ushort4(0, 0, 0, 0);
        }
        reinterpret_cast<ushort4*>(out)[i] = o;
    }
}

// ---------------- bf16 GEMM, B^T layout: C[m][n] = sum_k A[m][k]*B[n][k] + bias[n] ----------------
template<int OUT_BF16>
__global__ __launch_bounds__(256) void gemm_bt(
    const ushort* __restrict__ A, const ushort* __restrict__ B,
    const float* __restrict__ bias, void* __restrict__ Cout,
    int M, int N, int K, int Nreal, int ldC)
{
    __shared__ __align__(16) ushort As[128 * 64];
    __shared__ __align__(16) ushort Bs[128 * 64];
    const int tid = threadIdx.x;
    const int lane = tid & 63;
    const int w = tid >> 6;
    const int wr = w >> 1, wc = w & 1;
    const int m0 = blockIdx.y * 128, n0 = blockIdx.x * 128;

    f32x4 acc[4][4] = {};

    for (int k0 = 0; k0 < K; k0 += 64) {
        #pragma unroll
        for (int it = 0; it < 4; ++it) {
            int i = it * 256 + tid;
            int row = i >> 3;
            int col16 = (i ^ (row & 7)) & 7;
            const ushort* ga = A + (size_t)(m0 + row) * K + k0 + col16 * 8;
            ushort* la = As + (size_t)(it * 256 + (tid & ~63)) * 8;
            llds16(ga, la);
            const ushort* gb = B + (size_t)(n0 + row) * K + k0 + col16 * 8;
            ushort* lb = Bs + (size_t)(it * 256 + (tid & ~63)) * 8;
            llds16(gb, lb);
        }
        __syncthreads();
        #pragma unroll
        for (int kk = 0; kk < 2; ++kk) {
            bf16x8 a[4], b[4];
            #pragma unroll
            for (int mi = 0; mi < 4; ++mi) {
                int row = wr * 64 + mi * 16 + (lane & 15);
                int byte = row * 128 + kk * 64 + (lane >> 4) * 16;
                byte ^= (row & 7) << 4;
                a[mi] = *reinterpret_cast<const bf16x8*>(reinterpret_cast<const char*>(As) + byte);
            }
            #pragma unroll
            for (int ni = 0; ni < 4; ++ni) {
                int row = wc * 64 + ni * 16 + (lane & 15);
                int byte = row * 128 + kk * 64 + (lane >> 4) * 16;
                byte ^= (row & 7) << 4;
                b[ni] = *reinterpret_cast<const bf16x8*>(reinterpret_cast<const char*>(Bs) + byte);
            }
            #pragma unroll
            for (int mi = 0; mi < 4; ++mi)
                #pragma unroll
                for (int ni = 0; ni < 4; ++ni)
                    acc[mi][ni] = __builtin_amdgcn_mfma_f32_16x16x32_bf16(a[mi], b[ni], acc[mi][ni], 0, 0, 0);
        }
        __syncthreads();
    }

    #pragma unroll
    for (int mi = 0; mi < 4; ++mi) {
        int gr = m0 + wr * 64 + mi * 16 + (lane >> 4) * 4;
        #pragma unroll
        for (int ni = 0; ni < 4; ++ni) {
            int gc = n0 + wc * 64 + ni * 16 + (lane & 15);
            if (gc < Nreal) {
                float bv = bias[gc];
                #pragma unroll
                for (int r = 0; r < 4; ++r) {
                    float v = acc[mi][ni][r] + bv;
                    if (OUT_BF16)
                        ((ushort*)Cout)[(size_t)(gr + r) * ldC + gc] = f2b_bits(v);
                    else
                        ((float*)Cout)[(size_t)(gr + r) * ldC + gc] = v;
                }
            }
        }
    }
}

// ---------------- RoPE (YaRN) + split + q-prescale ----------------
__global__ __launch_bounds__(256) void rope_kernel(
    const ushort* __restrict__ qkv, const int* __restrict__ pos,
    ushort* __restrict__ q_ro, ushort* __restrict__ k_ro)
{
    __shared__ float cosv[32], sinv[32];
    const int s = blockIdx.x;
    const int tid = threadIdx.x;
    if (tid < 32) {
        int j = tid;
        const float logbase = logf(150000.0f);
        float freq = expf((float)j * (logbase / 32.0f));  // BASE^(j/32)
        float interp = 1.0f / (32.0f * freq);
        float extrap = 1.0f / freq;
        const float twopi = 6.283185307179586f;
        float low  = 32.0f * logf(4096.0f / (32.0f * twopi)) / logbase;
        float high = 32.0f * logf(4096.0f / (1.0f  * twopi)) / logbase;
        float ramp = ((float)j - low) / (high - low);
        float mask = 1.0f - fminf(fmaxf(ramp, 0.0f), 1.0f);
        float inv_freq = interp * (1.0f - mask) + extrap * mask;
        float ang = (float)pos[s] * inv_freq;
        const float conc = 0.1f * logf(32.0f) + 1.0f;
        cosv[j] = cosf(ang) * conc;
        sinv[j] = sinf(ang) * conc;
    }
    __syncthreads();
    #pragma unroll
    for (int it = 0; it < 8; ++it) {
        int idx = it * 256 + tid;
        int h = idx >> 5, j = idx & 31;
        const ushort* src = qkv + (size_t)s * QKV_DIM + h * HD;
        float x1 = b2f(src[j]), x2 = b2f(src[j + 32]);
        float c = cosv[j], sn = sinv[j];
        ushort* dst = q_ro + ((size_t)h * SEQ + s) * HD;
        dst[j]      = f2b_bits((x1 * c - x2 * sn) * 0.125f);
        dst[j + 32] = f2b_bits((x2 * c + x1 * sn) * 0.125f);
    }
    {
        int h = tid >> 5, j = tid & 31;
        const ushort* src = qkv + (size_t)s * QKV_DIM + Q_SZ + h * HD;
        float x1 = b2f(src[j]), x2 = b2f(src[j + 32]);
        float c = cosv[j], sn = sinv[j];
        ushort* dst = k_ro + ((size_t)h * SEQ + s) * HD;
        dst[j]      = f2b_bits(x1 * c - x2 * sn);
        dst[j + 32] = f2b_bits(x2 * c + x1 * sn);
    }
}

// ---------------- V transpose: qkv[s][4608 + kh*64 + d] -> vT[kh][d][s] ----------------
__global__ __launch_bounds__(256) void vtrans_kernel(const ushort* __restrict__ qkv, ushort* __restrict__ vT) {
    __shared__ ushort t[64][65];
    const int kh = blockIdx.x >> 5;
    const int s0 = (blockIdx.x & 31) * 64;
    const int tid = threadIdx.x;
    #pragma unroll
    for (int it = 0; it < 16; ++it) {
        int e = it * 256 + tid;
        int sl = e >> 6, d = e & 63;
        t[d][sl] = qkv[(size_t)(s0 + sl) * QKV_DIM + Q_SZ + K_SZ + kh * HD + d];
    }
    __syncthreads();
    #pragma unroll
    for (int it = 0; it < 16; ++it) {
        int e = it * 256 + tid;
        int d = e >> 6, sl = e & 63;
        vT[((size_t)kh * HD + d) * SEQ + s0 + sl] = t[d][sl];
    }
}

// ---------------- attention: flash-style, shared double-buffered K/V LDS tiles ----------------
// Block: 256 thr (4 waves). Handles 2 q-strips of 128 rows (paired p and 15-p for balance).
// Wave w owns 32 q-rows. K-tile 64x64 + V^T-tile 64x64 staged via global_load_lds with
// XOR-swizzle (inverse-swizzled global source), double-buffered, prefetched.
__global__ __launch_bounds__(256, 3) void attn_kernel(
    const ushort* __restrict__ q_ro, const ushort* __restrict__ k_ro,
    const ushort* __restrict__ vT, const float* __restrict__ sinks,
    ushort* __restrict__ attn_out)
{
    __shared__ __align__(16) ushort Kb[2][4096];
    __shared__ __align__(16) ushort Vb[2][4096];
    __shared__ __align__(16) ushort Pl[4][2048];

    const int tid = threadIdx.x;
    const int lane = tid & 63;
    const int w = tid >> 6;
    const int l15 = lane & 15;
    const int l4 = lane >> 4;

    // XCD-chunked bijective swizzle: 512 blocks, XCD x owns wgid [x*64, x*64+64) = one kv-head
    int wg = blockIdx.x;
    int wgid = (wg & 7) * 64 + (wg >> 3);
    const int kh = wgid >> 6;        // 0..7
    const int qh = (wgid >> 3) & 7;  // 0..7
    const int p = wgid & 7;          // 0..7
    const int h = kh * 8 + qh;

    const float snk = sinks[h];
    char* pbase = (char*)&Pl[w][0];

    auto stage = [&](int bs, int k0) {
        #pragma unroll
        for (int it = 0; it < 2; ++it) {
            int i = it * 256 + tid;
            int r = i >> 3;
            int cs = (i & 7) ^ (r & 7);
            llds16(k_ro + ((size_t)(kh * SEQ + k0 + r)) * 64 + cs * 8,
                   &Kb[bs][(it * 256 + (tid & ~63)) * 8]);
            llds16(vT + ((size_t)(kh * 64 + r)) * SEQ + k0 + cs * 8,
                   &Vb[bs][(it * 256 + (tid & ~63)) * 8]);
        }
    };

    for (int sidx = 0; sidx < 2; ++sidx) {
        const int qt = sidx ? (15 - p) : p;
        const int q0 = qt * 128;
        const int qw = q0 + w * 32;

        bf16x8 aq[2][2];
        #pragma unroll
        for (int qf = 0; qf < 2; ++qf)
            #pragma unroll
            for (int kc = 0; kc < 2; ++kc)
                aq[qf][kc] = *reinterpret_cast<const bf16x8*>(
                    q_ro + ((size_t)h * SEQ + qw + qf * 16 + l15) * HD + kc * 32 + l4 * 8);

        float m[2][4], l[2][4];
        f32x4 o[2][4] = {};
        #pragma unroll
        for (int qf = 0; qf < 2; ++qf)
            #pragma unroll
            for (int r = 0; r < 4; ++r) { m[qf][r] = snk; l[qf][r] = 1.0f; }

        const int kt0 = (qt >= 1) ? (2 * qt - 2) : 0;

        stage(0, kt0 * 64);
        __syncthreads();
        int bsel = 0;

        for (int kt = kt0; kt < SEQ / 64; ++kt) {
            const int k0 = kt * 64;
            if (kt + 1 < SEQ / 64) stage(bsel ^ 1, k0 + 64);

            // ---- QK^T ----
            f32x4 s[2][4];
            const f32x4 z = {0.f, 0.f, 0.f, 0.f};
            __builtin_amdgcn_s_setprio(1);
            #pragma unroll
            for (int c = 0; c < 4; ++c) {
                int rowK = c * 16 + l15;
                int byt0 = rowK * 128 + l4 * 16;
                byt0 ^= (rowK & 7) << 4;
                bf16x8 bk0 = *reinterpret_cast<const bf16x8*>((const char*)Kb[bsel] + byt0);
                s[0][c] = __builtin_amdgcn_mfma_f32_16x16x32_bf16(aq[0][0], bk0, z, 0, 0, 0);
                s[1][c] = __builtin_amdgcn_mfma_f32_16x16x32_bf16(aq[1][0], bk0, z, 0, 0, 0);
                bf16x8 bk1 = *reinterpret_cast<const bf16x8*>((const char*)Kb[bsel] + (byt0 ^ 64));
                s[0][c] = __builtin_amdgcn_mfma_f32_16x16x32_bf16(aq[0][1], bk1, s[0][c], 0, 0, 0);
                s[1][c] = __builtin_amdgcn_mfma_f32_16x16x32_bf16(aq[1][1], bk1, s[1][c], 0, 0, 0);
            }
            __builtin_amdgcn_s_setprio(0);

            // ---- sliding-window mask (only old keys masked: q - k > 128) ----
            if (k0 < qw - 97) {
                #pragma unroll
                for (int qf = 0; qf < 2; ++qf)
                    #pragma unroll
                    for (int c = 0; c < 4; ++c) {
                        int kg = k0 + c * 16 + l15;
                        #pragma unroll
                        for (int r = 0; r < 4; ++r) {
                            int qg = qw + qf * 16 + l4 * 4 + r;
                            if (qg - kg > 128) s[qf][c][r] = -1e30f;
                        }
                    }
            }

            // ---- online softmax ----
            float sc[2][4];
            #pragma unroll
            for (int qf = 0; qf < 2; ++qf)
                #pragma unroll
                for (int r = 0; r < 4; ++r) {
                    float t = fmaxf(fmaxf(s[qf][0][r], s[qf][1][r]), fmaxf(s[qf][2][r], s[qf][3][r]));
                    #pragma unroll
                    for (int d = 1; d <= 8; d <<= 1) t = fmaxf(t, __shfl_xor(t, d));
                    float mn = fmaxf(m[qf][r], t);
                    sc[qf][r] = __expf(m[qf][r] - mn);
                    m[qf][r] = mn;
                }
            #pragma unroll
            for (int qf = 0; qf < 2; ++qf) {
                float ps[4] = {0.f, 0.f, 0.f, 0.f};
                #pragma unroll
                for (int c = 0; c < 4; ++c)
                    #pragma unroll
                    for (int r = 0; r < 4; ++r) {
                        float pv = __expf(s[qf][c][r] - m[qf][r]);
                        ps[r] += pv;
                        int row = qf * 16 + l4 * 4 + r;
                        int byte = row * 128 + (c * 16 + l15) * 2;
                        byte ^= (row & 7) << 4;
                        *reinterpret_cast<ushort*>(pbase + byte) = f2b_bits(pv);
                    }
                #pragma unroll
                for (int r = 0; r < 4; ++r) {
                    float t = ps[r];
                    #pragma unroll
                    for (int d = 1; d <= 8; d <<= 1) t += __shfl_xor(t, d);
                    l[qf][r] = l[qf][r] * sc[qf][r] + t;
                }
                #pragma unroll
                for (int df = 0; df < 4; ++df)
                    #pragma unroll
                    for (int r = 0; r < 4; ++r)
                        o[qf][df][r] *= sc[qf][r];
            }

            // ---- PV ----
            __builtin_amdgcn_s_setprio(1);
            #pragma unroll
            for (int kc = 0; kc < 2; ++kc) {
                bf16x8 pa[2];
                #pragma unroll
                for (int qf = 0; qf < 2; ++qf) {
                    int row = qf * 16 + l15;
                    int byte = row * 128 + kc * 64 + l4 * 16;
                    byte ^= (row & 7) << 4;
                    pa[qf] = *reinterpret_cast<const bf16x8*>(pbase + byte);
                }
                #pragma unroll
                for (int df = 0; df < 4; ++df) {
                    int rowV = df * 16 + l15;
                    int byte = rowV * 128 + kc * 64 + l4 * 16;
                    byte ^= (rowV & 7) << 4;
                    bf16x8 bv = *reinterpret_cast<const bf16x8*>((const char*)Vb[bsel] + byte);
                    o[0][df] = __builtin_amdgcn_mfma_f32_16x16x32_bf16(pa[0], bv, o[0][df], 0, 0, 0);
                    o[1][df] = __builtin_amdgcn_mfma_f32_16x16x32_bf16(pa[1], bv, o[1][df], 0, 0, 0);
                }
            }
            __builtin_amdgcn_s_setprio(0);

            __syncthreads();  // drains vmcnt(0): next buffer staged; all waves done with cur
            bsel ^= 1;
        }

        // ---- epilogue ----
        #pragma unroll
        for (int qf = 0; qf < 2; ++qf) {
            float inv[4];
            #pragma unroll
            for (int r = 0; r < 4; ++r) inv[r] = 1.0f / l[qf][r];
            #pragma unroll
            for (int df = 0; df < 4; ++df)
                #pragma unroll
                for (int r = 0; r < 4; ++r) {
                    int row = qw + qf * 16 + l4 * 4 + r;
                    int col = df * 16 + l15;
                    attn_out[(size_t)row * Q_SZ + h * HD + col] = f2b_bits(o[qf][df][r] * inv[r]);
                }
        }
    }
}

extern "C" void kernel_launch(void* const* d_in, const int* in_sizes, int n_in,
                              void* d_out, int out_size, void* d_ws, size_t ws_size,
                              hipStream_t stream) {
    const float* hidden = (const float*)d_in[0];
    const float* qkv_w  = (const float*)d_in[1];
    const float* qkv_b  = (const float*)d_in[2];
    const float* o_w    = (const float*)d_in[3];
    const float* o_b    = (const float*)d_in[4];
    const float* sinks  = (const float*)d_in[5];
    const int*   pos    = (const int*)d_in[6];
    float* out = (float*)d_out;

    char* ws = (char*)d_ws;
    size_t off = 0;
    auto alloc = [&](size_t bytes) {
        char* p = ws + off;
        off += (bytes + 255) & ~(size_t)255;
        return p;
    };
    ushort* hs_bf   = (ushort*)alloc((size_t)SEQ * HIDDEN * 2);
    ushort* wqkv_bf = (ushort*)alloc((size_t)QKV_DIM * HIDDEN * 2);
    ushort* qkv_bf  = (ushort*)alloc((size_t)SEQ * QKV_DIM * 2);
    ushort* q_ro    = (ushort*)alloc((size_t)NQ * SEQ * HD * 2);
    ushort* k_ro    = (ushort*)alloc((size_t)NKV * SEQ * HD * 2);
    ushort* vT      = (ushort*)alloc((size_t)NKV * HD * SEQ * 2);
    ushort* attn_bf = (ushort*)alloc((size_t)SEQ * Q_SZ * 2);
    ushort* wo_bf   = (ushort*)alloc((size_t)OW_NPAD * OW_K * 2);

    convert_f32<<<2048, 256, 0, stream>>>(hidden, hs_bf, SEQ * HIDDEN / 4);
    convert_f32<<<2048, 256, 0, stream>>>(qkv_w, wqkv_bf, QKV_DIM * HIDDEN / 4);
    convert_ow<<<2048, 256, 0, stream>>>(o_w, wo_bf);

    gemm_bt<1><<<dim3(QKV_DIM / 128, SEQ / 128), 256, 0, stream>>>(
        hs_bf, wqkv_bf, qkv_b, qkv_bf, SEQ, QKV_DIM, HIDDEN, QKV_DIM, QKV_DIM);

    rope_kernel<<<SEQ, 256, 0, stream>>>(qkv_bf, pos, q_ro, k_ro);
    vtrans_kernel<<<NKV * 32, 256, 0, stream>>>(qkv_bf, vT);

    attn_kernel<<<512, 256, 0, stream>>>(q_ro, k_ro, vT, sinks, attn_bf);

    gemm_bt<0><<<dim3(OW_NPAD / 128, SEQ / 128), 256, 0, stream>>>(
        attn_bf, wo_bf, o_b, out, SEQ, OW_NPAD, OW_K, OW_N, OW_N);
}

// Round 3
// 324.172 us; speedup vs baseline: 1.9885x; 1.0689x over previous
//
#include <hip/hip_runtime.h>
#include <hip/hip_bf16.h>
#include <stdint.h>

typedef __attribute__((ext_vector_type(4))) float f32x4;
typedef __attribute__((ext_vector_type(8))) short bf16x8;

#define SEQ 2048
#define HIDDEN 2880
#define NQ 64
#define NKV 8
#define HD 64
#define QKV_DIM 5120
#define Q_SZ 4096
#define K_SZ 512
#define OW_N 2880
#define OW_NPAD 2944
#define OW_K 4096

__device__ __forceinline__ unsigned short f2b_bits(float f) {
    unsigned int x = __float_as_uint(f);
    unsigned int r = (x + 0x7fffu + ((x >> 16) & 1u)) >> 16;  // RNE
    return (unsigned short)r;
}
__device__ __forceinline__ float b2f(unsigned short u) {
    return __uint_as_float(((unsigned int)u) << 16);
}

__device__ __forceinline__ void llds16(const ushort* g, ushort* l) {
    __builtin_amdgcn_global_load_lds(
        (const __attribute__((address_space(1))) void*)g,
        (__attribute__((address_space(3))) void*)l, 16, 0, 0);
}

// ---------------- fp32 -> bf16 conversion ----------------
__global__ void convert_f32(const float* __restrict__ in, ushort* __restrict__ out, int n4) {
    int i = blockIdx.x * blockDim.x + threadIdx.x;
    int stride = gridDim.x * blockDim.x;
    for (; i < n4; i += stride) {
        float4 v = reinterpret_cast<const float4*>(in)[i];
        ushort4 o = make_ushort4(f2b_bits(v.x), f2b_bits(v.y), f2b_bits(v.z), f2b_bits(v.w));
        reinterpret_cast<ushort4*>(out)[i] = o;
    }
}

// o_w [2880][4096] -> bf16 padded to [2944][4096] (pad rows zero)
__global__ void convert_ow(const float* __restrict__ in, ushort* __restrict__ out) {
    int i = blockIdx.x * blockDim.x + threadIdx.x;
    const int n4 = OW_NPAD * OW_K / 4;
    int stride = gridDim.x * blockDim.x;
    for (; i < n4; i += stride) {
        int row = (i * 4) >> 12;  // /4096
        ushort4 o;
        if (row < OW_N) {
            float4 v = reinterpret_cast<const float4*>(in)[i];
            o = make_ushort4(f2b_bits(v.x), f2b_bits(v.y), f2b_bits(v.z), f2b_bits(v.w));
        } else {
            o = make_ushort4(0, 0, 0, 0);
        }
        reinterpret_cast<ushort4*>(out)[i] = o;
    }
}

// ---------------- bf16 GEMM, B^T layout: C[m][n] = sum_k A[m][k]*B[n][k] + bias[n] ----------------
template<int OUT_BF16>
__global__ __launch_bounds__(256) void gemm_bt(
    const ushort* __restrict__ A, const ushort* __restrict__ B,
    const float* __restrict__ bias, void* __restrict__ Cout,
    int M, int N, int K, int Nreal, int ldC)
{
    __shared__ __align__(16) ushort As[128 * 64];
    __shared__ __align__(16) ushort Bs[128 * 64];
    const int tid = threadIdx.x;
    const int lane = tid & 63;
    const int w = tid >> 6;
    const int wr = w >> 1, wc = w & 1;
    const int m0 = blockIdx.y * 128, n0 = blockIdx.x * 128;

    f32x4 acc[4][4] = {};

    for (int k0 = 0; k0 < K; k0 += 64) {
        #pragma unroll
        for (int it = 0; it < 4; ++it) {
            int i = it * 256 + tid;
            int row = i >> 3;
            int col16 = (i ^ (row & 7)) & 7;
            const ushort* ga = A + (size_t)(m0 + row) * K + k0 + col16 * 8;
            ushort* la = As + (size_t)(it * 256 + (tid & ~63)) * 8;
            llds16(ga, la);
            const ushort* gb = B + (size_t)(n0 + row) * K + k0 + col16 * 8;
            ushort* lb = Bs + (size_t)(it * 256 + (tid & ~63)) * 8;
            llds16(gb, lb);
        }
        __syncthreads();
        #pragma unroll
        for (int kk = 0; kk < 2; ++kk) {
            bf16x8 a[4], b[4];
            #pragma unroll
            for (int mi = 0; mi < 4; ++mi) {
                int row = wr * 64 + mi * 16 + (lane & 15);
                int byte = row * 128 + kk * 64 + (lane >> 4) * 16;
                byte ^= (row & 7) << 4;
                a[mi] = *reinterpret_cast<const bf16x8*>(reinterpret_cast<const char*>(As) + byte);
            }
            #pragma unroll
            for (int ni = 0; ni < 4; ++ni) {
                int row = wc * 64 + ni * 16 + (lane & 15);
                int byte = row * 128 + kk * 64 + (lane >> 4) * 16;
                byte ^= (row & 7) << 4;
                b[ni] = *reinterpret_cast<const bf16x8*>(reinterpret_cast<const char*>(Bs) + byte);
            }
            #pragma unroll
            for (int mi = 0; mi < 4; ++mi)
                #pragma unroll
                for (int ni = 0; ni < 4; ++ni)
                    acc[mi][ni] = __builtin_amdgcn_mfma_f32_16x16x32_bf16(a[mi], b[ni], acc[mi][ni], 0, 0, 0);
        }
        __syncthreads();
    }

    #pragma unroll
    for (int mi = 0; mi < 4; ++mi) {
        int gr = m0 + wr * 64 + mi * 16 + (lane >> 4) * 4;
        #pragma unroll
        for (int ni = 0; ni < 4; ++ni) {
            int gc = n0 + wc * 64 + ni * 16 + (lane & 15);
            if (gc < Nreal) {
                float bv = bias[gc];
                #pragma unroll
                for (int r = 0; r < 4; ++r) {
                    float v = acc[mi][ni][r] + bv;
                    if (OUT_BF16)
                        ((ushort*)Cout)[(size_t)(gr + r) * ldC + gc] = f2b_bits(v);
                    else
                        ((float*)Cout)[(size_t)(gr + r) * ldC + gc] = v;
                }
            }
        }
    }
}

// ---------------- RoPE (YaRN) + split + q-prescale ----------------
__global__ __launch_bounds__(256) void rope_kernel(
    const ushort* __restrict__ qkv, const int* __restrict__ pos,
    ushort* __restrict__ q_ro, ushort* __restrict__ k_ro)
{
    __shared__ float cosv[32], sinv[32];
    const int s = blockIdx.x;
    const int tid = threadIdx.x;
    if (tid < 32) {
        int j = tid;
        const float logbase = logf(150000.0f);
        float freq = expf((float)j * (logbase / 32.0f));  // BASE^(j/32)
        float interp = 1.0f / (32.0f * freq);
        float extrap = 1.0f / freq;
        const float twopi = 6.283185307179586f;
        float low  = 32.0f * logf(4096.0f / (32.0f * twopi)) / logbase;
        float high = 32.0f * logf(4096.0f / (1.0f  * twopi)) / logbase;
        float ramp = ((float)j - low) / (high - low);
        float mask = 1.0f - fminf(fmaxf(ramp, 0.0f), 1.0f);
        float inv_freq = interp * (1.0f - mask) + extrap * mask;
        float ang = (float)pos[s] * inv_freq;
        const float conc = 0.1f * logf(32.0f) + 1.0f;
        cosv[j] = cosf(ang) * conc;
        sinv[j] = sinf(ang) * conc;
    }
    __syncthreads();
    #pragma unroll
    for (int it = 0; it < 8; ++it) {
        int idx = it * 256 + tid;
        int h = idx >> 5, j = idx & 31;
        const ushort* src = qkv + (size_t)s * QKV_DIM + h * HD;
        float x1 = b2f(src[j]), x2 = b2f(src[j + 32]);
        float c = cosv[j], sn = sinv[j];
        ushort* dst = q_ro + ((size_t)h * SEQ + s) * HD;
        dst[j]      = f2b_bits((x1 * c - x2 * sn) * 0.125f);
        dst[j + 32] = f2b_bits((x2 * c + x1 * sn) * 0.125f);
    }
    {
        int h = tid >> 5, j = tid & 31;
        const ushort* src = qkv + (size_t)s * QKV_DIM + Q_SZ + h * HD;
        float x1 = b2f(src[j]), x2 = b2f(src[j + 32]);
        float c = cosv[j], sn = sinv[j];
        ushort* dst = k_ro + ((size_t)h * SEQ + s) * HD;
        dst[j]      = f2b_bits(x1 * c - x2 * sn);
        dst[j + 32] = f2b_bits(x2 * c + x1 * sn);
    }
}

// ---------------- V transpose: qkv[s][4608 + kh*64 + d] -> vT[kh][d][s] ----------------
__global__ __launch_bounds__(256) void vtrans_kernel(const ushort* __restrict__ qkv, ushort* __restrict__ vT) {
    __shared__ ushort t[64][65];
    const int kh = blockIdx.x >> 5;
    const int s0 = (blockIdx.x & 31) * 64;
    const int tid = threadIdx.x;
    #pragma unroll
    for (int it = 0; it < 16; ++it) {
        int e = it * 256 + tid;
        int sl = e >> 6, d = e & 63;
        t[d][sl] = qkv[(size_t)(s0 + sl) * QKV_DIM + Q_SZ + K_SZ + kh * HD + d];
    }
    __syncthreads();
    #pragma unroll
    for (int it = 0; it < 16; ++it) {
        int e = it * 256 + tid;
        int d = e >> 6, sl = e & 63;
        vT[((size_t)kh * HD + d) * SEQ + s0 + sl] = t[d][sl];
    }
}

// ---------------- attention v3: 64-row strips, 4 waves x 16 q-rows, 1024 blocks ----------------
// Pairing (p, 31-p) over 32 strips for balance (~35-37 tiles/block).
// K-tile 64x64 + V^T-tile 64x64 double-buffered via global_load_lds + XOR swizzle.
// LDS = 16K + 16K + 8K = 40960 B -> exactly 4 blocks/CU -> 16 waves/CU.
__global__ __launch_bounds__(256, 4) void attn_kernel(
    const ushort* __restrict__ q_ro, const ushort* __restrict__ k_ro,
    const ushort* __restrict__ vT, const float* __restrict__ sinks,
    ushort* __restrict__ attn_out)
{
    __shared__ __align__(16) ushort Kb[2][4096];
    __shared__ __align__(16) ushort Vb[2][4096];
    __shared__ __align__(16) ushort Pl[4][1024];

    const int tid = threadIdx.x;
    const int lane = tid & 63;
    const int w = tid >> 6;
    const int l15 = lane & 15;
    const int l4 = lane >> 4;

    // XCD-chunked bijective swizzle: 1024 blocks, XCD x owns wgid [x*128, (x+1)*128) = one kv-head
    int wg = blockIdx.x;
    int wgid = (wg & 7) * 128 + (wg >> 3);
    const int kh = wgid >> 7;        // 0..7
    const int qh = (wgid >> 4) & 7;  // 0..7
    const int p = wgid & 15;         // 0..15
    const int h = kh * 8 + qh;

    const float snk = sinks[h];
    char* pbase = (char*)&Pl[w][0];

    auto stage = [&](int bs, int k0) {
        #pragma unroll
        for (int it = 0; it < 2; ++it) {
            int i = it * 256 + tid;
            int r = i >> 3;
            int cs = (i & 7) ^ (r & 7);
            llds16(k_ro + ((size_t)(kh * SEQ + k0 + r)) * 64 + cs * 8,
                   &Kb[bs][(it * 256 + (tid & ~63)) * 8]);
            llds16(vT + ((size_t)(kh * 64 + r)) * SEQ + k0 + cs * 8,
                   &Vb[bs][(it * 256 + (tid & ~63)) * 8]);
        }
    };

    for (int sidx = 0; sidx < 2; ++sidx) {
        const int qt = sidx ? (31 - p) : p;
        const int q0 = qt * 64;
        const int qw = q0 + w * 16;

        bf16x8 aq[2];
        #pragma unroll
        for (int kc = 0; kc < 2; ++kc)
            aq[kc] = *reinterpret_cast<const bf16x8*>(
                q_ro + ((size_t)h * SEQ + qw + l15) * HD + kc * 32 + l4 * 8);

        float m[4], l[4];
        f32x4 o[4] = {};
        #pragma unroll
        for (int r = 0; r < 4; ++r) { m[r] = snk; l[r] = 1.0f; }

        const int kt0 = (qt >= 2) ? (qt - 2) : 0;

        stage(0, kt0 * 64);
        __syncthreads();
        int bsel = 0;

        for (int kt = kt0; kt < SEQ / 64; ++kt) {
            const int k0 = kt * 64;
            if (kt + 1 < SEQ / 64) stage(bsel ^ 1, k0 + 64);

            // ---- QK^T ----
            f32x4 s[4];
            const f32x4 z = {0.f, 0.f, 0.f, 0.f};
            __builtin_amdgcn_s_setprio(1);
            #pragma unroll
            for (int c = 0; c < 4; ++c) {
                int rowK = c * 16 + l15;
                int byt0 = rowK * 128 + l4 * 16;
                byt0 ^= (rowK & 7) << 4;
                bf16x8 bk0 = *reinterpret_cast<const bf16x8*>((const char*)Kb[bsel] + byt0);
                s[c] = __builtin_amdgcn_mfma_f32_16x16x32_bf16(aq[0], bk0, z, 0, 0, 0);
                bf16x8 bk1 = *reinterpret_cast<const bf16x8*>((const char*)Kb[bsel] + (byt0 ^ 64));
                s[c] = __builtin_amdgcn_mfma_f32_16x16x32_bf16(aq[1], bk1, s[c], 0, 0, 0);
            }
            __builtin_amdgcn_s_setprio(0);

            // ---- sliding-window mask (only old keys masked: q - k > 128) ----
            if (k0 < qw - 113) {
                #pragma unroll
                for (int c = 0; c < 4; ++c) {
                    int kg = k0 + c * 16 + l15;
                    #pragma unroll
                    for (int r = 0; r < 4; ++r) {
                        int qg = qw + l4 * 4 + r;
                        if (qg - kg > 128) s[c][r] = -1e30f;
                    }
                }
            }

            // ---- online softmax ----
            float sc[4];
            #pragma unroll
            for (int r = 0; r < 4; ++r) {
                float t = fmaxf(fmaxf(s[0][r], s[1][r]), fmaxf(s[2][r], s[3][r]));
                #pragma unroll
                for (int d = 1; d <= 8; d <<= 1) t = fmaxf(t, __shfl_xor(t, d));
                float mn = fmaxf(m[r], t);
                sc[r] = __expf(m[r] - mn);
                m[r] = mn;
            }
            {
                float ps[4] = {0.f, 0.f, 0.f, 0.f};
                #pragma unroll
                for (int c = 0; c < 4; ++c)
                    #pragma unroll
                    for (int r = 0; r < 4; ++r) {
                        float pv = __expf(s[c][r] - m[r]);
                        ps[r] += pv;
                        int row = l4 * 4 + r;
                        int byte = row * 128 + (c * 16 + l15) * 2;
                        byte ^= (row & 7) << 4;
                        *reinterpret_cast<ushort*>(pbase + byte) = f2b_bits(pv);
                    }
                #pragma unroll
                for (int r = 0; r < 4; ++r) {
                    float t = ps[r];
                    #pragma unroll
                    for (int d = 1; d <= 8; d <<= 1) t += __shfl_xor(t, d);
                    l[r] = l[r] * sc[r] + t;
                }
                #pragma unroll
                for (int df = 0; df < 4; ++df)
                    #pragma unroll
                    for (int r = 0; r < 4; ++r)
                        o[df][r] *= sc[r];
            }

            // ---- PV ----
            __builtin_amdgcn_s_setprio(1);
            #pragma unroll
            for (int kc = 0; kc < 2; ++kc) {
                int rowP = l15;
                int byteP = rowP * 128 + kc * 64 + l4 * 16;
                byteP ^= (rowP & 7) << 4;
                bf16x8 pa = *reinterpret_cast<const bf16x8*>(pbase + byteP);
                #pragma unroll
                for (int df = 0; df < 4; ++df) {
                    int rowV = df * 16 + l15;
                    int byte = rowV * 128 + kc * 64 + l4 * 16;
                    byte ^= (rowV & 7) << 4;
                    bf16x8 bv = *reinterpret_cast<const bf16x8*>((const char*)Vb[bsel] + byte);
                    o[df] = __builtin_amdgcn_mfma_f32_16x16x32_bf16(pa, bv, o[df], 0, 0, 0);
                }
            }
            __builtin_amdgcn_s_setprio(0);

            __syncthreads();
            bsel ^= 1;
        }

        // ---- epilogue ----
        {
            float inv[4];
            #pragma unroll
            for (int r = 0; r < 4; ++r) inv[r] = 1.0f / l[r];
            #pragma unroll
            for (int df = 0; df < 4; ++df)
                #pragma unroll
                for (int r = 0; r < 4; ++r) {
                    int row = qw + l4 * 4 + r;
                    int col = df * 16 + l15;
                    attn_out[(size_t)row * Q_SZ + h * HD + col] = f2b_bits(o[df][r] * inv[r]);
                }
        }
    }
}

extern "C" void kernel_launch(void* const* d_in, const int* in_sizes, int n_in,
                              void* d_out, int out_size, void* d_ws, size_t ws_size,
                              hipStream_t stream) {
    const float* hidden = (const float*)d_in[0];
    const float* qkv_w  = (const float*)d_in[1];
    const float* qkv_b  = (const float*)d_in[2];
    const float* o_w    = (const float*)d_in[3];
    const float* o_b    = (const float*)d_in[4];
    const float* sinks  = (const float*)d_in[5];
    const int*   pos    = (const int*)d_in[6];
    float* out = (float*)d_out;

    char* ws = (char*)d_ws;
    size_t off = 0;
    auto alloc = [&](size_t bytes) {
        char* p = ws + off;
        off += (bytes + 255) & ~(size_t)255;
        return p;
    };
    ushort* hs_bf   = (ushort*)alloc((size_t)SEQ * HIDDEN * 2);
    ushort* wqkv_bf = (ushort*)alloc((size_t)QKV_DIM * HIDDEN * 2);
    ushort* qkv_bf  = (ushort*)alloc((size_t)SEQ * QKV_DIM * 2);
    ushort* q_ro    = (ushort*)alloc((size_t)NQ * SEQ * HD * 2);
    ushort* k_ro    = (ushort*)alloc((size_t)NKV * SEQ * HD * 2);
    ushort* vT      = (ushort*)alloc((size_t)NKV * HD * SEQ * 2);
    ushort* attn_bf = (ushort*)alloc((size_t)SEQ * Q_SZ * 2);
    ushort* wo_bf   = (ushort*)alloc((size_t)OW_NPAD * OW_K * 2);

    convert_f32<<<2048, 256, 0, stream>>>(hidden, hs_bf, SEQ * HIDDEN / 4);
    convert_f32<<<2048, 256, 0, stream>>>(qkv_w, wqkv_bf, QKV_DIM * HIDDEN / 4);
    convert_ow<<<2048, 256, 0, stream>>>(o_w, wo_bf);

    gemm_bt<1><<<dim3(QKV_DIM / 128, SEQ / 128), 256, 0, stream>>>(
        hs_bf, wqkv_bf, qkv_b, qkv_bf, SEQ, QKV_DIM, HIDDEN, QKV_DIM, QKV_DIM);

    rope_kernel<<<SEQ, 256, 0, stream>>>(qkv_bf, pos, q_ro, k_ro);
    vtrans_kernel<<<NKV * 32, 256, 0, stream>>>(qkv_bf, vT);

    attn_kernel<<<1024, 256, 0, stream>>>(q_ro, k_ro, vT, sinks, attn_bf);

    gemm_bt<0><<<dim3(OW_NPAD / 128, SEQ / 128), 256, 0, stream>>>(
        attn_bf, wo_bf, o_b, out, SEQ, OW_NPAD, OW_K, OW_N, OW_N);
}

// Round 4
// 289.626 us; speedup vs baseline: 2.2256x; 1.1193x over previous
//
#include <hip/hip_runtime.h>
#include <hip/hip_bf16.h>
#include <stdint.h>

typedef __attribute__((ext_vector_type(4))) float f32x4;
typedef __attribute__((ext_vector_type(8))) short bf16x8;

#define SEQ 2048
#define HIDDEN 2880
#define NQ 64
#define NKV 8
#define HD 64
#define QKV_DIM 5120
#define Q_SZ 4096
#define K_SZ 512
#define OW_N 2880
#define OW_NPAD 2944
#define OW_K 4096

__device__ __forceinline__ unsigned short f2b_bits(float f) {
    unsigned int x = __float_as_uint(f);
    unsigned int r = (x + 0x7fffu + ((x >> 16) & 1u)) >> 16;  // RNE
    return (unsigned short)r;
}
__device__ __forceinline__ float b2f(unsigned short u) {
    return __uint_as_float(((unsigned int)u) << 16);
}

__device__ __forceinline__ void llds16(const ushort* g, ushort* l) {
    __builtin_amdgcn_global_load_lds(
        (const __attribute__((address_space(1))) void*)g,
        (__attribute__((address_space(3))) void*)l, 16, 0, 0);
}

// ---------------- fp32 -> bf16 conversion ----------------
__global__ void convert_f32(const float* __restrict__ in, ushort* __restrict__ out, int n4) {
    int i = blockIdx.x * blockDim.x + threadIdx.x;
    int stride = gridDim.x * blockDim.x;
    for (; i < n4; i += stride) {
        float4 v = reinterpret_cast<const float4*>(in)[i];
        ushort4 o = make_ushort4(f2b_bits(v.x), f2b_bits(v.y), f2b_bits(v.z), f2b_bits(v.w));
        reinterpret_cast<ushort4*>(out)[i] = o;
    }
}

// o_w [2880][4096] -> bf16 padded to [2944][4096] (pad rows zero)
__global__ void convert_ow(const float* __restrict__ in, ushort* __restrict__ out) {
    int i = blockIdx.x * blockDim.x + threadIdx.x;
    const int n4 = OW_NPAD * OW_K / 4;
    int stride = gridDim.x * blockDim.x;
    for (; i < n4; i += stride) {
        int row = (i * 4) >> 12;  // /4096
        ushort4 o;
        if (row < OW_N) {
            float4 v = reinterpret_cast<const float4*>(in)[i];
            o = make_ushort4(f2b_bits(v.x), f2b_bits(v.y), f2b_bits(v.z), f2b_bits(v.w));
        } else {
            o = make_ushort4(0, 0, 0, 0);
        }
        reinterpret_cast<ushort4*>(out)[i] = o;
    }
}

// ---------------- bf16 GEMM, B^T layout: C[m][n] = sum_k A[m][k]*B[n][k] + bias[n] ----------------
template<int OUT_BF16>
__global__ __launch_bounds__(256) void gemm_bt(
    const ushort* __restrict__ A, const ushort* __restrict__ B,
    const float* __restrict__ bias, void* __restrict__ Cout,
    int M, int N, int K, int Nreal, int ldC)
{
    __shared__ __align__(16) ushort As[128 * 64];
    __shared__ __align__(16) ushort Bs[128 * 64];
    const int tid = threadIdx.x;
    const int lane = tid & 63;
    const int w = tid >> 6;
    const int wr = w >> 1, wc = w & 1;
    const int m0 = blockIdx.y * 128, n0 = blockIdx.x * 128;

    f32x4 acc[4][4] = {};

    for (int k0 = 0; k0 < K; k0 += 64) {
        #pragma unroll
        for (int it = 0; it < 4; ++it) {
            int i = it * 256 + tid;
            int row = i >> 3;
            int col16 = (i ^ (row & 7)) & 7;
            const ushort* ga = A + (size_t)(m0 + row) * K + k0 + col16 * 8;
            ushort* la = As + (size_t)(it * 256 + (tid & ~63)) * 8;
            llds16(ga, la);
            const ushort* gb = B + (size_t)(n0 + row) * K + k0 + col16 * 8;
            ushort* lb = Bs + (size_t)(it * 256 + (tid & ~63)) * 8;
            llds16(gb, lb);
        }
        __syncthreads();
        #pragma unroll
        for (int kk = 0; kk < 2; ++kk) {
            bf16x8 a[4], b[4];
            #pragma unroll
            for (int mi = 0; mi < 4; ++mi) {
                int row = wr * 64 + mi * 16 + (lane & 15);
                int byte = row * 128 + kk * 64 + (lane >> 4) * 16;
                byte ^= (row & 7) << 4;
                a[mi] = *reinterpret_cast<const bf16x8*>(reinterpret_cast<const char*>(As) + byte);
            }
            #pragma unroll
            for (int ni = 0; ni < 4; ++ni) {
                int row = wc * 64 + ni * 16 + (lane & 15);
                int byte = row * 128 + kk * 64 + (lane >> 4) * 16;
                byte ^= (row & 7) << 4;
                b[ni] = *reinterpret_cast<const bf16x8*>(reinterpret_cast<const char*>(Bs) + byte);
            }
            #pragma unroll
            for (int mi = 0; mi < 4; ++mi)
                #pragma unroll
                for (int ni = 0; ni < 4; ++ni)
                    acc[mi][ni] = __builtin_amdgcn_mfma_f32_16x16x32_bf16(a[mi], b[ni], acc[mi][ni], 0, 0, 0);
        }
        __syncthreads();
    }

    #pragma unroll
    for (int mi = 0; mi < 4; ++mi) {
        int gr = m0 + wr * 64 + mi * 16 + (lane >> 4) * 4;
        #pragma unroll
        for (int ni = 0; ni < 4; ++ni) {
            int gc = n0 + wc * 64 + ni * 16 + (lane & 15);
            if (gc < Nreal) {
                float bv = bias[gc];
                #pragma unroll
                for (int r = 0; r < 4; ++r) {
                    float v = acc[mi][ni][r] + bv;
                    if (OUT_BF16)
                        ((ushort*)Cout)[(size_t)(gr + r) * ldC + gc] = f2b_bits(v);
                    else
                        ((float*)Cout)[(size_t)(gr + r) * ldC + gc] = v;
                }
            }
        }
    }
}

// ---------------- RoPE (YaRN) + split + q-prescale ----------------
// Q is pre-scaled by HEAD_DIM^-0.5 * log2(e) so attention uses exp2 directly.
__global__ __launch_bounds__(256) void rope_kernel(
    const ushort* __restrict__ qkv, const int* __restrict__ pos,
    ushort* __restrict__ q_ro, ushort* __restrict__ k_ro)
{
    __shared__ float cosv[32], sinv[32];
    const int s = blockIdx.x;
    const int tid = threadIdx.x;
    if (tid < 32) {
        int j = tid;
        const float logbase = logf(150000.0f);
        float freq = expf((float)j * (logbase / 32.0f));  // BASE^(j/32)
        float interp = 1.0f / (32.0f * freq);
        float extrap = 1.0f / freq;
        const float twopi = 6.283185307179586f;
        float low  = 32.0f * logf(4096.0f / (32.0f * twopi)) / logbase;
        float high = 32.0f * logf(4096.0f / (1.0f  * twopi)) / logbase;
        float ramp = ((float)j - low) / (high - low);
        float mask = 1.0f - fminf(fmaxf(ramp, 0.0f), 1.0f);
        float inv_freq = interp * (1.0f - mask) + extrap * mask;
        float ang = (float)pos[s] * inv_freq;
        const float conc = 0.1f * logf(32.0f) + 1.0f;
        cosv[j] = cosf(ang) * conc;
        sinv[j] = sinf(ang) * conc;
    }
    __syncthreads();
    const float qsc = 0.125f * 1.4426950408889634f;  // scale * log2(e)
    #pragma unroll
    for (int it = 0; it < 8; ++it) {
        int idx = it * 256 + tid;
        int h = idx >> 5, j = idx & 31;
        const ushort* src = qkv + (size_t)s * QKV_DIM + h * HD;
        float x1 = b2f(src[j]), x2 = b2f(src[j + 32]);
        float c = cosv[j], sn = sinv[j];
        ushort* dst = q_ro + ((size_t)h * SEQ + s) * HD;
        dst[j]      = f2b_bits((x1 * c - x2 * sn) * qsc);
        dst[j + 32] = f2b_bits((x2 * c + x1 * sn) * qsc);
    }
    {
        int h = tid >> 5, j = tid & 31;
        const ushort* src = qkv + (size_t)s * QKV_DIM + Q_SZ + h * HD;
        float x1 = b2f(src[j]), x2 = b2f(src[j + 32]);
        float c = cosv[j], sn = sinv[j];
        ushort* dst = k_ro + ((size_t)h * SEQ + s) * HD;
        dst[j]      = f2b_bits(x1 * c - x2 * sn);
        dst[j + 32] = f2b_bits(x2 * c + x1 * sn);
    }
}

// ---------------- V transpose: qkv[s][4608 + kh*64 + d] -> vT[kh][d][s] ----------------
__global__ __launch_bounds__(256) void vtrans_kernel(const ushort* __restrict__ qkv, ushort* __restrict__ vT) {
    __shared__ ushort t[64][65];
    const int kh = blockIdx.x >> 5;
    const int s0 = (blockIdx.x & 31) * 64;
    const int tid = threadIdx.x;
    #pragma unroll
    for (int it = 0; it < 16; ++it) {
        int e = it * 256 + tid;
        int sl = e >> 6, d = e & 63;
        t[d][sl] = qkv[(size_t)(s0 + sl) * QKV_DIM + Q_SZ + K_SZ + kh * HD + d];
    }
    __syncthreads();
    #pragma unroll
    for (int it = 0; it < 16; ++it) {
        int e = it * 256 + tid;
        int d = e >> 6, sl = e & 63;
        vT[((size_t)kh * HD + d) * SEQ + s0 + sl] = t[d][sl];
    }
}

// ---------------- attention v4: fixed-max softmax (no max-reduce, no rescale), ----------------
// l via ones-MFMA. Kb double-buffered, Vb single-buffered (counted vmcnt + raw barrier).
// LDS = 16K + 8K + 8K = 32KB -> 5 blocks/CU.
__global__ __launch_bounds__(256, 5) void attn_kernel(
    const ushort* __restrict__ q_ro, const ushort* __restrict__ k_ro,
    const ushort* __restrict__ vT, const float* __restrict__ sinks,
    ushort* __restrict__ attn_out)
{
    __shared__ __align__(16) ushort Kb[2][4096];
    __shared__ __align__(16) ushort Vb[4096];
    __shared__ __align__(16) ushort Pl[4][1024];

    const int tid = threadIdx.x;
    const int lane = tid & 63;
    const int w = tid >> 6;
    const int l15 = lane & 15;
    const int l4 = lane >> 4;

    // XCD-chunked bijective swizzle: 1024 blocks, XCD x owns wgid [x*128,(x+1)*128) = one kv-head
    int wg = blockIdx.x;
    int wgid = (wg & 7) * 128 + (wg >> 3);
    const int kh = wgid >> 7;        // 0..7
    const int qh = (wgid >> 4) & 7;  // 0..7
    const int pp = wgid & 15;        // 0..15
    const int h = kh * 8 + qh;

    const float snk = sinks[h];
    char* pbase = (char*)&Pl[w][0];

    const short oneb = (short)0x3F80;  // bf16 1.0
    const bf16x8 bones = {oneb, oneb, oneb, oneb, oneb, oneb, oneb, oneb};

    auto stageK = [&](int bs, int k0) {
        #pragma unroll
        for (int it = 0; it < 2; ++it) {
            int i = it * 256 + tid;
            int r = i >> 3;
            int cs = (i & 7) ^ (r & 7);
            llds16(k_ro + ((size_t)(kh * SEQ + k0 + r)) * 64 + cs * 8,
                   &Kb[bs][(it * 256 + (tid & ~63)) * 8]);
        }
    };
    auto stageV = [&](int k0) {
        #pragma unroll
        for (int it = 0; it < 2; ++it) {
            int i = it * 256 + tid;
            int r = i >> 3;
            int cs = (i & 7) ^ (r & 7);
            llds16(vT + ((size_t)(kh * 64 + r)) * SEQ + k0 + cs * 8,
                   &Vb[(it * 256 + (tid & ~63)) * 8]);
        }
    };

    for (int sidx = 0; sidx < 2; ++sidx) {
        const int qt = sidx ? (31 - pp) : pp;
        const int q0 = qt * 64;
        const int qw = q0 + w * 16;

        bf16x8 aq[2];
        #pragma unroll
        for (int kc = 0; kc < 2; ++kc)
            aq[kc] = *reinterpret_cast<const bf16x8*>(
                q_ro + ((size_t)h * SEQ + qw + l15) * HD + kc * 32 + l4 * 8);

        f32x4 o[4] = {};
        f32x4 lacc = {0.f, 0.f, 0.f, 0.f};

        const int kt0 = (qt >= 2) ? (qt - 2) : 0;
        int cur = 0;

        stageK(0, kt0 * 64);
        __syncthreads();  // K(kt0) resident for all waves

        auto tile_body = [&](int kt, bool pref) {
            const int k0 = kt * 64;
            stageV(k0);                         // oldest in-flight: V(t)
            if (pref) stageK(cur ^ 1, k0 + 64); // newest: K(t+1)

            // ---- QK^T (K already resident) ----
            f32x4 s[4];
            const f32x4 z = {0.f, 0.f, 0.f, 0.f};
            __builtin_amdgcn_s_setprio(1);
            #pragma unroll
            for (int c = 0; c < 4; ++c) {
                int rowK = c * 16 + l15;
                int byt0 = rowK * 128 + l4 * 16;
                byt0 ^= (rowK & 7) << 4;
                bf16x8 bk0 = *reinterpret_cast<const bf16x8*>((const char*)Kb[cur] + byt0);
                s[c] = __builtin_amdgcn_mfma_f32_16x16x32_bf16(aq[0], bk0, z, 0, 0, 0);
                bf16x8 bk1 = *reinterpret_cast<const bf16x8*>((const char*)Kb[cur] + (byt0 ^ 64));
                s[c] = __builtin_amdgcn_mfma_f32_16x16x32_bf16(aq[1], bk1, s[c], 0, 0, 0);
            }
            __builtin_amdgcn_s_setprio(0);

            // ---- sliding-window mask (only old keys: q - k > 128) ----
            if (k0 < qw - 113) {
                #pragma unroll
                for (int c = 0; c < 4; ++c) {
                    int kg = k0 + c * 16 + l15;
                    #pragma unroll
                    for (int r = 0; r < 4; ++r) {
                        int qg = qw + l4 * 4 + r;
                        if (qg - kg > 128) s[c][r] = -1e30f;
                    }
                }
            }

            // ---- fixed-max softmax: p = exp2(s) (Q pre-scaled by log2e), store bf16 ----
            #pragma unroll
            for (int c = 0; c < 4; ++c)
                #pragma unroll
                for (int r = 0; r < 4; ++r) {
                    float pv = exp2f(s[c][r]);
                    int row = l4 * 4 + r;
                    int byte = row * 128 + (c * 16 + l15) * 2;
                    byte ^= (row & 7) << 4;
                    *reinterpret_cast<ushort*>(pbase + byte) = f2b_bits(pv);
                }

            // ---- wait own V loads (K prefetch stays in flight), then all-waves barrier ----
            if (pref) asm volatile("s_waitcnt vmcnt(2)\n\ts_barrier" ::: "memory");
            else      asm volatile("s_waitcnt vmcnt(0)\n\ts_barrier" ::: "memory");

            // ---- PV + l via ones-MFMA ----
            __builtin_amdgcn_s_setprio(1);
            #pragma unroll
            for (int kc = 0; kc < 2; ++kc) {
                int byteP = l15 * 128 + kc * 64 + l4 * 16;
                byteP ^= (l15 & 7) << 4;
                bf16x8 pa = *reinterpret_cast<const bf16x8*>(pbase + byteP);
                lacc = __builtin_amdgcn_mfma_f32_16x16x32_bf16(pa, bones, lacc, 0, 0, 0);
                #pragma unroll
                for (int df = 0; df < 4; ++df) {
                    int rowV = df * 16 + l15;
                    int byte = rowV * 128 + kc * 64 + l4 * 16;
                    byte ^= (rowV & 7) << 4;
                    bf16x8 bv = *reinterpret_cast<const bf16x8*>((const char*)Vb + byte);
                    o[df] = __builtin_amdgcn_mfma_f32_16x16x32_bf16(pa, bv, o[df], 0, 0, 0);
                }
            }
            __builtin_amdgcn_s_setprio(0);

            __syncthreads();  // drains vmcnt(0): K(t+1) resident; Vb free for overwrite
            cur ^= 1;
        };

        for (int kt = kt0; kt < SEQ / 64 - 1; ++kt) tile_body(kt, true);
        tile_body(SEQ / 64 - 1, false);

        // ---- epilogue: denom = sum(p) + exp(sink) ----
        {
            const float es = exp2f(snk * 1.4426950408889634f);
            float inv[4];
            #pragma unroll
            for (int r = 0; r < 4; ++r) inv[r] = 1.0f / (lacc[r] + es);
            #pragma unroll
            for (int df = 0; df < 4; ++df)
                #pragma unroll
                for (int r = 0; r < 4; ++r) {
                    int row = qw + l4 * 4 + r;
                    int col = df * 16 + l15;
                    attn_out[(size_t)row * Q_SZ + h * HD + col] = f2b_bits(o[df][r] * inv[r]);
                }
        }
    }
}

extern "C" void kernel_launch(void* const* d_in, const int* in_sizes, int n_in,
                              void* d_out, int out_size, void* d_ws, size_t ws_size,
                              hipStream_t stream) {
    const float* hidden = (const float*)d_in[0];
    const float* qkv_w  = (const float*)d_in[1];
    const float* qkv_b  = (const float*)d_in[2];
    const float* o_w    = (const float*)d_in[3];
    const float* o_b    = (const float*)d_in[4];
    const float* sinks  = (const float*)d_in[5];
    const int*   pos    = (const int*)d_in[6];
    float* out = (float*)d_out;

    char* ws = (char*)d_ws;
    size_t off = 0;
    auto alloc = [&](size_t bytes) {
        char* p = ws + off;
        off += (bytes + 255) & ~(size_t)255;
        return p;
    };
    ushort* hs_bf   = (ushort*)alloc((size_t)SEQ * HIDDEN * 2);
    ushort* wqkv_bf = (ushort*)alloc((size_t)QKV_DIM * HIDDEN * 2);
    ushort* qkv_bf  = (ushort*)alloc((size_t)SEQ * QKV_DIM * 2);
    ushort* q_ro    = (ushort*)alloc((size_t)NQ * SEQ * HD * 2);
    ushort* k_ro    = (ushort*)alloc((size_t)NKV * SEQ * HD * 2);
    ushort* vT      = (ushort*)alloc((size_t)NKV * HD * SEQ * 2);
    ushort* attn_bf = (ushort*)alloc((size_t)SEQ * Q_SZ * 2);
    ushort* wo_bf   = (ushort*)alloc((size_t)OW_NPAD * OW_K * 2);

    convert_f32<<<2048, 256, 0, stream>>>(hidden, hs_bf, SEQ * HIDDEN / 4);
    convert_f32<<<2048, 256, 0, stream>>>(qkv_w, wqkv_bf, QKV_DIM * HIDDEN / 4);
    convert_ow<<<2048, 256, 0, stream>>>(o_w, wo_bf);

    gemm_bt<1><<<dim3(QKV_DIM / 128, SEQ / 128), 256, 0, stream>>>(
        hs_bf, wqkv_bf, qkv_b, qkv_bf, SEQ, QKV_DIM, HIDDEN, QKV_DIM, QKV_DIM);

    rope_kernel<<<SEQ, 256, 0, stream>>>(qkv_bf, pos, q_ro, k_ro);
    vtrans_kernel<<<NKV * 32, 256, 0, stream>>>(qkv_bf, vT);

    attn_kernel<<<1024, 256, 0, stream>>>(q_ro, k_ro, vT, sinks, attn_bf);

    gemm_bt<0><<<dim3(OW_NPAD / 128, SEQ / 128), 256, 0, stream>>>(
        attn_bf, wo_bf, o_b, out, SEQ, OW_NPAD, OW_K, OW_N, OW_N);
}

// Round 5
// 275.211 us; speedup vs baseline: 2.3422x; 1.0524x over previous
//
#include <hip/hip_runtime.h>
#include <hip/hip_bf16.h>
#include <stdint.h>

typedef __attribute__((ext_vector_type(4))) float f32x4;
typedef __attribute__((ext_vector_type(8))) short bf16x8;

#define SEQ 2048
#define HIDDEN 2880
#define NQ 64
#define NKV 8
#define HD 64
#define QKV_DIM 5120
#define Q_SZ 4096
#define K_SZ 512
#define OW_N 2880
#define OW_NPAD 2944
#define OW_K 4096

__device__ __forceinline__ unsigned short f2b_bits(float f) {
    unsigned int x = __float_as_uint(f);
    unsigned int r = (x + 0x7fffu + ((x >> 16) & 1u)) >> 16;  // RNE
    return (unsigned short)r;
}
__device__ __forceinline__ float b2f(unsigned short u) {
    return __uint_as_float(((unsigned int)u) << 16);
}

__device__ __forceinline__ void llds16(const ushort* g, ushort* l) {
    __builtin_amdgcn_global_load_lds(
        (const __attribute__((address_space(1))) void*)g,
        (__attribute__((address_space(3))) void*)l, 16, 0, 0);
}

// ---------------- fp32 -> bf16 conversion ----------------
__global__ void convert_f32(const float* __restrict__ in, ushort* __restrict__ out, int n4) {
    int i = blockIdx.x * blockDim.x + threadIdx.x;
    int stride = gridDim.x * blockDim.x;
    for (; i < n4; i += stride) {
        float4 v = reinterpret_cast<const float4*>(in)[i];
        ushort4 o = make_ushort4(f2b_bits(v.x), f2b_bits(v.y), f2b_bits(v.z), f2b_bits(v.w));
        reinterpret_cast<ushort4*>(out)[i] = o;
    }
}

// o_w [2880][4096] -> bf16 padded to [2944][4096] (pad rows zero)
__global__ void convert_ow(const float* __restrict__ in, ushort* __restrict__ out) {
    int i = blockIdx.x * blockDim.x + threadIdx.x;
    const int n4 = OW_NPAD * OW_K / 4;
    int stride = gridDim.x * blockDim.x;
    for (; i < n4; i += stride) {
        int row = (i * 4) >> 12;  // /4096
        ushort4 o;
        if (row < OW_N) {
            float4 v = reinterpret_cast<const float4*>(in)[i];
            o = make_ushort4(f2b_bits(v.x), f2b_bits(v.y), f2b_bits(v.z), f2b_bits(v.w));
        } else {
            o = make_ushort4(0, 0, 0, 0);
        }
        reinterpret_cast<ushort4*>(out)[i] = o;
    }
}

// ---------------- bf16 GEMM, B^T layout: C[m][n] = sum_k A[m][k]*B[n][k] + bias[n] ----------------
template<int OUT_BF16>
__global__ __launch_bounds__(256) void gemm_bt(
    const ushort* __restrict__ A, const ushort* __restrict__ B,
    const float* __restrict__ bias, void* __restrict__ Cout,
    int M, int N, int K, int Nreal, int ldC)
{
    __shared__ __align__(16) ushort As[128 * 64];
    __shared__ __align__(16) ushort Bs[128 * 64];
    const int tid = threadIdx.x;
    const int lane = tid & 63;
    const int w = tid >> 6;
    const int wr = w >> 1, wc = w & 1;
    const int m0 = blockIdx.y * 128, n0 = blockIdx.x * 128;

    f32x4 acc[4][4] = {};

    for (int k0 = 0; k0 < K; k0 += 64) {
        #pragma unroll
        for (int it = 0; it < 4; ++it) {
            int i = it * 256 + tid;
            int row = i >> 3;
            int col16 = (i ^ (row & 7)) & 7;
            const ushort* ga = A + (size_t)(m0 + row) * K + k0 + col16 * 8;
            ushort* la = As + (size_t)(it * 256 + (tid & ~63)) * 8;
            llds16(ga, la);
            const ushort* gb = B + (size_t)(n0 + row) * K + k0 + col16 * 8;
            ushort* lb = Bs + (size_t)(it * 256 + (tid & ~63)) * 8;
            llds16(gb, lb);
        }
        __syncthreads();
        #pragma unroll
        for (int kk = 0; kk < 2; ++kk) {
            bf16x8 a[4], b[4];
            #pragma unroll
            for (int mi = 0; mi < 4; ++mi) {
                int row = wr * 64 + mi * 16 + (lane & 15);
                int byte = row * 128 + kk * 64 + (lane >> 4) * 16;
                byte ^= (row & 7) << 4;
                a[mi] = *reinterpret_cast<const bf16x8*>(reinterpret_cast<const char*>(As) + byte);
            }
            #pragma unroll
            for (int ni = 0; ni < 4; ++ni) {
                int row = wc * 64 + ni * 16 + (lane & 15);
                int byte = row * 128 + kk * 64 + (lane >> 4) * 16;
                byte ^= (row & 7) << 4;
                b[ni] = *reinterpret_cast<const bf16x8*>(reinterpret_cast<const char*>(Bs) + byte);
            }
            #pragma unroll
            for (int mi = 0; mi < 4; ++mi)
                #pragma unroll
                for (int ni = 0; ni < 4; ++ni)
                    acc[mi][ni] = __builtin_amdgcn_mfma_f32_16x16x32_bf16(a[mi], b[ni], acc[mi][ni], 0, 0, 0);
        }
        __syncthreads();
    }

    #pragma unroll
    for (int mi = 0; mi < 4; ++mi) {
        int gr = m0 + wr * 64 + mi * 16 + (lane >> 4) * 4;
        #pragma unroll
        for (int ni = 0; ni < 4; ++ni) {
            int gc = n0 + wc * 64 + ni * 16 + (lane & 15);
            if (gc < Nreal) {
                float bv = bias[gc];
                #pragma unroll
                for (int r = 0; r < 4; ++r) {
                    float v = acc[mi][ni][r] + bv;
                    if (OUT_BF16)
                        ((ushort*)Cout)[(size_t)(gr + r) * ldC + gc] = f2b_bits(v);
                    else
                        ((float*)Cout)[(size_t)(gr + r) * ldC + gc] = v;
                }
            }
        }
    }
}

// ---------------- RoPE (YaRN) + split + q-prescale ----------------
// Q is pre-scaled by HEAD_DIM^-0.5 * log2(e) so attention uses exp2 directly.
__global__ __launch_bounds__(256) void rope_kernel(
    const ushort* __restrict__ qkv, const int* __restrict__ pos,
    ushort* __restrict__ q_ro, ushort* __restrict__ k_ro)
{
    __shared__ float cosv[32], sinv[32];
    const int s = blockIdx.x;
    const int tid = threadIdx.x;
    if (tid < 32) {
        int j = tid;
        const float logbase = logf(150000.0f);
        float freq = expf((float)j * (logbase / 32.0f));  // BASE^(j/32)
        float interp = 1.0f / (32.0f * freq);
        float extrap = 1.0f / freq;
        const float twopi = 6.283185307179586f;
        float low  = 32.0f * logf(4096.0f / (32.0f * twopi)) / logbase;
        float high = 32.0f * logf(4096.0f / (1.0f  * twopi)) / logbase;
        float ramp = ((float)j - low) / (high - low);
        float mask = 1.0f - fminf(fmaxf(ramp, 0.0f), 1.0f);
        float inv_freq = interp * (1.0f - mask) + extrap * mask;
        float ang = (float)pos[s] * inv_freq;
        const float conc = 0.1f * logf(32.0f) + 1.0f;
        cosv[j] = cosf(ang) * conc;
        sinv[j] = sinf(ang) * conc;
    }
    __syncthreads();
    const float qsc = 0.125f * 1.4426950408889634f;  // scale * log2(e)
    #pragma unroll
    for (int it = 0; it < 8; ++it) {
        int idx = it * 256 + tid;
        int h = idx >> 5, j = idx & 31;
        const ushort* src = qkv + (size_t)s * QKV_DIM + h * HD;
        float x1 = b2f(src[j]), x2 = b2f(src[j + 32]);
        float c = cosv[j], sn = sinv[j];
        ushort* dst = q_ro + ((size_t)h * SEQ + s) * HD;
        dst[j]      = f2b_bits((x1 * c - x2 * sn) * qsc);
        dst[j + 32] = f2b_bits((x2 * c + x1 * sn) * qsc);
    }
    {
        int h = tid >> 5, j = tid & 31;
        const ushort* src = qkv + (size_t)s * QKV_DIM + Q_SZ + h * HD;
        float x1 = b2f(src[j]), x2 = b2f(src[j + 32]);
        float c = cosv[j], sn = sinv[j];
        ushort* dst = k_ro + ((size_t)h * SEQ + s) * HD;
        dst[j]      = f2b_bits(x1 * c - x2 * sn);
        dst[j + 32] = f2b_bits(x2 * c + x1 * sn);
    }
}

// ---------------- V transpose: qkv[s][4608 + kh*64 + d] -> vT[kh][d][s] ----------------
__global__ __launch_bounds__(256) void vtrans_kernel(const ushort* __restrict__ qkv, ushort* __restrict__ vT) {
    __shared__ ushort t[64][65];
    const int kh = blockIdx.x >> 5;
    const int s0 = (blockIdx.x & 31) * 64;
    const int tid = threadIdx.x;
    #pragma unroll
    for (int it = 0; it < 16; ++it) {
        int e = it * 256 + tid;
        int sl = e >> 6, d = e & 63;
        t[d][sl] = qkv[(size_t)(s0 + sl) * QKV_DIM + Q_SZ + K_SZ + kh * HD + d];
    }
    __syncthreads();
    #pragma unroll
    for (int it = 0; it < 16; ++it) {
        int e = it * 256 + tid;
        int d = e >> 6, sl = e & 63;
        vT[((size_t)kh * HD + d) * SEQ + s0 + sl] = t[d][sl];
    }
}

// ---------------- attention v5: swapped QK^T (S^T in regs), fixed-max softmax, ----------------
// cvt_pk bf16 pack + ds_write_b64 P stores, double-buffered K and V, one barrier/tile.
// LDS = 16K + 16K + 8K = 40KB -> 4 blocks/CU (grid-capped anyway).
__global__ __launch_bounds__(256, 4) void attn_kernel(
    const ushort* __restrict__ q_ro, const ushort* __restrict__ k_ro,
    const ushort* __restrict__ vT, const float* __restrict__ sinks,
    ushort* __restrict__ attn_out)
{
    __shared__ __align__(16) ushort Kb[2][4096];
    __shared__ __align__(16) ushort Vb[2][4096];
    __shared__ __align__(16) ushort Pl[4][1024];

    const int tid = threadIdx.x;
    const int lane = tid & 63;
    const int w = tid >> 6;
    const int l15 = lane & 15;
    const int l4 = lane >> 4;

    // XCD-chunked bijective swizzle: 1024 blocks, XCD x owns wgid [x*128,(x+1)*128) = one kv-head
    int wg = blockIdx.x;
    int wgid = (wg & 7) * 128 + (wg >> 3);
    const int kh = wgid >> 7;        // 0..7
    const int qh = (wgid >> 4) & 7;  // 0..7
    const int pp = wgid & 15;        // 0..15
    const int h = kh * 8 + qh;

    const float snk = sinks[h];
    char* pbase = (char*)&Pl[w][0];

    const short oneb = (short)0x3F80;  // bf16 1.0
    const bf16x8 bones = {oneb, oneb, oneb, oneb, oneb, oneb, oneb, oneb};

    // ---- hoisted staging addresses (2 chunks/thread/array) ----
    const int i0 = tid, i1 = 256 + tid;
    const int r0 = i0 >> 3, cs0 = (i0 ^ r0) & 7;
    const int r1 = i1 >> 3, cs1 = (i1 ^ r1) & 7;
    const ushort* gK0 = k_ro + (size_t)kh * (SEQ * 64) + r0 * 64 + cs0 * 8;
    const ushort* gK1 = k_ro + (size_t)kh * (SEQ * 64) + r1 * 64 + cs1 * 8;
    const ushort* gV0 = vT + ((size_t)kh * 64 + r0) * SEQ + cs0 * 8;
    const ushort* gV1 = vT + ((size_t)kh * 64 + r1) * SEQ + cs1 * 8;
    const int ld0 = (tid & ~63) * 8, ld1 = (256 + (tid & ~63)) * 8;

    // ---- per-lane LDS byte bases ----
    const int swz = (l15 & 7) << 4;
    const int kvbase = l15 * 128 + ((l4 * 16) ^ swz);  // K/V frag reads (^ kc*64, + c/df*2048)
    const int pwbase = l15 * 128 + ((l4 * 8) ^ swz);   // P writes (^ c*32)

    auto stage = [&](int bs, int k0) {
        llds16(gK0 + k0 * 64, &Kb[bs][ld0]);
        llds16(gK1 + k0 * 64, &Kb[bs][ld1]);
        llds16(gV0 + k0,      &Vb[bs][ld0]);
        llds16(gV1 + k0,      &Vb[bs][ld1]);
    };

    for (int sidx = 0; sidx < 2; ++sidx) {
        const int qt = sidx ? (31 - pp) : pp;
        const int q0 = qt * 64;
        const int qw = q0 + w * 16;

        bf16x8 aq[2];
        #pragma unroll
        for (int kc = 0; kc < 2; ++kc)
            aq[kc] = *reinterpret_cast<const bf16x8*>(
                q_ro + ((size_t)h * SEQ + qw + l15) * HD + kc * 32 + l4 * 8);

        f32x4 o[4] = {};
        f32x4 lacc = {0.f, 0.f, 0.f, 0.f};

        const int kt0 = (qt >= 2) ? (qt - 2) : 0;
        int cur = 0;

        stage(0, kt0 * 64);
        __syncthreads();

        for (int kt = kt0; kt < SEQ / 64; ++kt) {
            const int k0 = kt * 64;
            if (kt + 1 < SEQ / 64) stage(cur ^ 1, k0 + 64);

            // ---- QK^T swapped: S^T[k][q] = K x Q ----
            f32x4 s[4];
            const f32x4 z = {0.f, 0.f, 0.f, 0.f};
            const char* kbp = (const char*)Kb[cur];
            __builtin_amdgcn_s_setprio(1);
            #pragma unroll
            for (int c = 0; c < 4; ++c) {
                bf16x8 bk0 = *reinterpret_cast<const bf16x8*>(kbp + c * 2048 + kvbase);
                s[c] = __builtin_amdgcn_mfma_f32_16x16x32_bf16(bk0, aq[0], z, 0, 0, 0);
                bf16x8 bk1 = *reinterpret_cast<const bf16x8*>(kbp + c * 2048 + (kvbase ^ 64));
                s[c] = __builtin_amdgcn_mfma_f32_16x16x32_bf16(bk1, aq[1], s[c], 0, 0, 0);
            }
            __builtin_amdgcn_s_setprio(0);

            // ---- sliding-window mask (only old keys: q - k > 128); first tile only ----
            if (k0 < qw - 113) {
                int thr = qw + l15 - 128 - k0;  // local k < thr -> masked
                #pragma unroll
                for (int c = 0; c < 4; ++c)
                    #pragma unroll
                    for (int r = 0; r < 4; ++r)
                        if (c * 16 + l4 * 4 + r < thr) s[c][r] = -1e30f;
            }

            // ---- fixed-max softmax: p = exp2(s); pack pairs; b64 store to P[q][k] ----
            #pragma unroll
            for (int c = 0; c < 4; ++c) {
                float p0 = exp2f(s[c][0]), p1 = exp2f(s[c][1]);
                float p2 = exp2f(s[c][2]), p3 = exp2f(s[c][3]);
                unsigned int pk0, pk1;
                asm("v_cvt_pk_bf16_f32 %0, %1, %2" : "=v"(pk0) : "v"(p0), "v"(p1));
                asm("v_cvt_pk_bf16_f32 %0, %1, %2" : "=v"(pk1) : "v"(p2), "v"(p3));
                uint2 pv; pv.x = pk0; pv.y = pk1;
                *reinterpret_cast<uint2*>(pbase + (pwbase ^ (c * 32))) = pv;
            }

            // ---- PV + l via ones-MFMA ----
            const char* vbp = (const char*)Vb[cur];
            __builtin_amdgcn_s_setprio(1);
            #pragma unroll
            for (int kc = 0; kc < 2; ++kc) {
                bf16x8 pa = *reinterpret_cast<const bf16x8*>(pbase + (kvbase ^ (kc * 64)) - (kvbase & ~2047) + (l15 * 128 + ((l4 * 16) ^ swz) - l15 * 128));
                pa = *reinterpret_cast<const bf16x8*>(pbase + ((l15 * 128 + ((l4 * 16) ^ swz)) ^ (kc * 64)));
                lacc = __builtin_amdgcn_mfma_f32_16x16x32_bf16(pa, bones, lacc, 0, 0, 0);
                #pragma unroll
                for (int df = 0; df < 4; ++df) {
                    bf16x8 bv = *reinterpret_cast<const bf16x8*>(vbp + df * 2048 + (kvbase ^ (kc * 64)));
                    o[df] = __builtin_amdgcn_mfma_f32_16x16x32_bf16(pa, bv, o[df], 0, 0, 0);
                }
            }
            __builtin_amdgcn_s_setprio(0);

            __syncthreads();  // drains vmcnt(0): next tile staged; all waves done with cur
            cur ^= 1;
        }

        // ---- epilogue: denom = sum(p) + exp(sink) ----
        {
            const float es = exp2f(snk * 1.4426950408889634f);
            float inv[4];
            #pragma unroll
            for (int r = 0; r < 4; ++r) inv[r] = 1.0f / (lacc[r] + es);
            #pragma unroll
            for (int df = 0; df < 4; ++df)
                #pragma unroll
                for (int r = 0; r < 4; ++r) {
                    int row = qw + l4 * 4 + r;
                    int col = df * 16 + l15;
                    attn_out[(size_t)row * Q_SZ + h * HD + col] = f2b_bits(o[df][r] * inv[r]);
                }
        }
    }
}

extern "C" void kernel_launch(void* const* d_in, const int* in_sizes, int n_in,
                              void* d_out, int out_size, void* d_ws, size_t ws_size,
                              hipStream_t stream) {
    const float* hidden = (const float*)d_in[0];
    const float* qkv_w  = (const float*)d_in[1];
    const float* qkv_b  = (const float*)d_in[2];
    const float* o_w    = (const float*)d_in[3];
    const float* o_b    = (const float*)d_in[4];
    const float* sinks  = (const float*)d_in[5];
    const int*   pos    = (const int*)d_in[6];
    float* out = (float*)d_out;

    char* ws = (char*)d_ws;
    size_t off = 0;
    auto alloc = [&](size_t bytes) {
        char* p = ws + off;
        off += (bytes + 255) & ~(size_t)255;
        return p;
    };
    ushort* hs_bf   = (ushort*)alloc((size_t)SEQ * HIDDEN * 2);
    ushort* wqkv_bf = (ushort*)alloc((size_t)QKV_DIM * HIDDEN * 2);
    ushort* qkv_bf  = (ushort*)alloc((size_t)SEQ * QKV_DIM * 2);
    ushort* q_ro    = (ushort*)alloc((size_t)NQ * SEQ * HD * 2);
    ushort* k_ro    = (ushort*)alloc((size_t)NKV * SEQ * HD * 2);
    ushort* vT      = (ushort*)alloc((size_t)NKV * HD * SEQ * 2);
    ushort* attn_bf = (ushort*)alloc((size_t)SEQ * Q_SZ * 2);
    ushort* wo_bf   = (ushort*)alloc((size_t)OW_NPAD * OW_K * 2);

    convert_f32<<<2048, 256, 0, stream>>>(hidden, hs_bf, SEQ * HIDDEN / 4);
    convert_f32<<<2048, 256, 0, stream>>>(qkv_w, wqkv_bf, QKV_DIM * HIDDEN / 4);
    convert_ow<<<2048, 256, 0, stream>>>(o_w, wo_bf);

    gemm_bt<1><<<dim3(QKV_DIM / 128, SEQ / 128), 256, 0, stream>>>(
        hs_bf, wqkv_bf, qkv_b, qkv_bf, SEQ, QKV_DIM, HIDDEN, QKV_DIM, QKV_DIM);

    rope_kernel<<<SEQ, 256, 0, stream>>>(qkv_bf, pos, q_ro, k_ro);
    vtrans_kernel<<<NKV * 32, 256, 0, stream>>>(qkv_bf, vT);

    attn_kernel<<<1024, 256, 0, stream>>>(q_ro, k_ro, vT, sinks, attn_bf);

    gemm_bt<0><<<dim3(OW_NPAD / 128, SEQ / 128), 256, 0, stream>>>(
        attn_bf, wo_bf, o_b, out, SEQ, OW_NPAD, OW_K, OW_N, OW_N);
}

// Round 6
// 272.723 us; speedup vs baseline: 2.3636x; 1.0091x over previous
//
#include <hip/hip_runtime.h>
#include <hip/hip_bf16.h>
#include <stdint.h>

typedef __attribute__((ext_vector_type(4))) float f32x4;
typedef __attribute__((ext_vector_type(8))) short bf16x8;

#define SEQ 2048
#define HIDDEN 2880
#define NQ 64
#define NKV 8
#define HD 64
#define QKV_DIM 5120
#define Q_SZ 4096
#define K_SZ 512
#define OW_N 2880
#define OW_NPAD 2944
#define OW_K 4096

__device__ __forceinline__ unsigned short f2b_bits(float f) {
    unsigned int x = __float_as_uint(f);
    unsigned int r = (x + 0x7fffu + ((x >> 16) & 1u)) >> 16;  // RNE
    return (unsigned short)r;
}
__device__ __forceinline__ float b2f(unsigned short u) {
    return __uint_as_float(((unsigned int)u) << 16);
}

__device__ __forceinline__ void llds16(const ushort* g, ushort* l) {
    __builtin_amdgcn_global_load_lds(
        (const __attribute__((address_space(1))) void*)g,
        (__attribute__((address_space(3))) void*)l, 16, 0, 0);
}

// ---------------- fused fp32 -> bf16 conversion (hidden + qkv_w + o_w padded) ----------------
__global__ void convert_all(const float* __restrict__ hidden, const float* __restrict__ qkv_w,
                            const float* __restrict__ o_w, ushort* __restrict__ hs_bf,
                            ushort* __restrict__ wqkv_bf, ushort* __restrict__ wo_bf) {
    const int N1 = SEQ * HIDDEN / 4;                 // 1,474,560
    const int N2 = N1 + QKV_DIM * HIDDEN / 4;        // 5,160,960
    const int N3 = N2 + OW_NPAD * OW_K / 4;          // 8,175,616
    int i = blockIdx.x * blockDim.x + threadIdx.x;
    int stride = gridDim.x * blockDim.x;
    for (; i < N3; i += stride) {
        const float* src;
        ushort* dst;
        int j;
        if (i < N1) {
            j = i; src = hidden; dst = hs_bf;
        } else if (i < N2) {
            j = i - N1; src = qkv_w; dst = wqkv_bf;
        } else {
            j = i - N2; src = o_w; dst = wo_bf;
            if ((j >> 10) >= OW_N) {  // padded rows (row = j*4/4096)
                reinterpret_cast<ushort4*>(dst)[j] = make_ushort4(0, 0, 0, 0);
                continue;
            }
        }
        float4 v = reinterpret_cast<const float4*>(src)[j];
        reinterpret_cast<ushort4*>(dst)[j] =
            make_ushort4(f2b_bits(v.x), f2b_bits(v.y), f2b_bits(v.z), f2b_bits(v.w));
    }
}

// ---------------- bf16 GEMM, B^T layout: C[m][n] = sum_k A[m][k]*B[n][k] + bias[n] ----------------
// 1D grid, chunked-XCD swizzle: XCD x owns a contiguous wgid chunk => contiguous N-panel
// (B-panel fits the XCD's 4MB L2); M-tile iterates fastest within the chunk.
// Requires gridDim.x % 8 == 0 and M/128 == 16.
template<int OUT_BF16>
__global__ __launch_bounds__(256) void gemm_bt(
    const ushort* __restrict__ A, const ushort* __restrict__ B,
    const float* __restrict__ bias, void* __restrict__ Cout,
    int M, int N, int K, int Nreal, int ldC)
{
    __shared__ __align__(16) ushort As[128 * 64];
    __shared__ __align__(16) ushort Bs[128 * 64];
    const int tid = threadIdx.x;
    const int lane = tid & 63;
    const int w = tid >> 6;
    const int wr = w >> 1, wc = w & 1;

    const int nwg = gridDim.x;
    const int per = nwg >> 3;
    const int wgid = (blockIdx.x & 7) * per + (blockIdx.x >> 3);
    const int m0 = (wgid & 15) * 128;   // M-tile fastest (16 M-tiles)
    const int n0 = (wgid >> 4) * 128;   // N-tile chunk-contiguous per XCD

    f32x4 acc[4][4] = {};

    for (int k0 = 0; k0 < K; k0 += 64) {
        #pragma unroll
        for (int it = 0; it < 4; ++it) {
            int i = it * 256 + tid;
            int row = i >> 3;
            int col16 = (i ^ (row & 7)) & 7;
            const ushort* ga = A + (size_t)(m0 + row) * K + k0 + col16 * 8;
            ushort* la = As + (size_t)(it * 256 + (tid & ~63)) * 8;
            llds16(ga, la);
            const ushort* gb = B + (size_t)(n0 + row) * K + k0 + col16 * 8;
            ushort* lb = Bs + (size_t)(it * 256 + (tid & ~63)) * 8;
            llds16(gb, lb);
        }
        __syncthreads();
        #pragma unroll
        for (int kk = 0; kk < 2; ++kk) {
            bf16x8 a[4], b[4];
            #pragma unroll
            for (int mi = 0; mi < 4; ++mi) {
                int row = wr * 64 + mi * 16 + (lane & 15);
                int byte = row * 128 + kk * 64 + (lane >> 4) * 16;
                byte ^= (row & 7) << 4;
                a[mi] = *reinterpret_cast<const bf16x8*>(reinterpret_cast<const char*>(As) + byte);
            }
            #pragma unroll
            for (int ni = 0; ni < 4; ++ni) {
                int row = wc * 64 + ni * 16 + (lane & 15);
                int byte = row * 128 + kk * 64 + (lane >> 4) * 16;
                byte ^= (row & 7) << 4;
                b[ni] = *reinterpret_cast<const bf16x8*>(reinterpret_cast<const char*>(Bs) + byte);
            }
            #pragma unroll
            for (int mi = 0; mi < 4; ++mi)
                #pragma unroll
                for (int ni = 0; ni < 4; ++ni)
                    acc[mi][ni] = __builtin_amdgcn_mfma_f32_16x16x32_bf16(a[mi], b[ni], acc[mi][ni], 0, 0, 0);
        }
        __syncthreads();
    }

    #pragma unroll
    for (int mi = 0; mi < 4; ++mi) {
        int gr = m0 + wr * 64 + mi * 16 + (lane >> 4) * 4;
        #pragma unroll
        for (int ni = 0; ni < 4; ++ni) {
            int gc = n0 + wc * 64 + ni * 16 + (lane & 15);
            if (gc < Nreal) {
                float bv = bias[gc];
                #pragma unroll
                for (int r = 0; r < 4; ++r) {
                    float v = acc[mi][ni][r] + bv;
                    if (OUT_BF16)
                        ((ushort*)Cout)[(size_t)(gr + r) * ldC + gc] = f2b_bits(v);
                    else
                        ((float*)Cout)[(size_t)(gr + r) * ldC + gc] = v;
                }
            }
        }
    }
}

// ---------------- RoPE (YaRN) + split + q-prescale ----------------
// Q is pre-scaled by HEAD_DIM^-0.5 * log2(e) so attention uses exp2 directly.
__global__ __launch_bounds__(256) void rope_kernel(
    const ushort* __restrict__ qkv, const int* __restrict__ pos,
    ushort* __restrict__ q_ro, ushort* __restrict__ k_ro)
{
    __shared__ float cosv[32], sinv[32];
    const int s = blockIdx.x;
    const int tid = threadIdx.x;
    if (tid < 32) {
        int j = tid;
        const float logbase = logf(150000.0f);
        float freq = expf((float)j * (logbase / 32.0f));  // BASE^(j/32)
        float interp = 1.0f / (32.0f * freq);
        float extrap = 1.0f / freq;
        const float twopi = 6.283185307179586f;
        float low  = 32.0f * logf(4096.0f / (32.0f * twopi)) / logbase;
        float high = 32.0f * logf(4096.0f / (1.0f  * twopi)) / logbase;
        float ramp = ((float)j - low) / (high - low);
        float mask = 1.0f - fminf(fmaxf(ramp, 0.0f), 1.0f);
        float inv_freq = interp * (1.0f - mask) + extrap * mask;
        float ang = (float)pos[s] * inv_freq;
        const float conc = 0.1f * logf(32.0f) + 1.0f;
        cosv[j] = cosf(ang) * conc;
        sinv[j] = sinf(ang) * conc;
    }
    __syncthreads();
    const float qsc = 0.125f * 1.4426950408889634f;  // scale * log2(e)
    #pragma unroll
    for (int it = 0; it < 8; ++it) {
        int idx = it * 256 + tid;
        int h = idx >> 5, j = idx & 31;
        const ushort* src = qkv + (size_t)s * QKV_DIM + h * HD;
        float x1 = b2f(src[j]), x2 = b2f(src[j + 32]);
        float c = cosv[j], sn = sinv[j];
        ushort* dst = q_ro + ((size_t)h * SEQ + s) * HD;
        dst[j]      = f2b_bits((x1 * c - x2 * sn) * qsc);
        dst[j + 32] = f2b_bits((x2 * c + x1 * sn) * qsc);
    }
    {
        int h = tid >> 5, j = tid & 31;
        const ushort* src = qkv + (size_t)s * QKV_DIM + Q_SZ + h * HD;
        float x1 = b2f(src[j]), x2 = b2f(src[j + 32]);
        float c = cosv[j], sn = sinv[j];
        ushort* dst = k_ro + ((size_t)h * SEQ + s) * HD;
        dst[j]      = f2b_bits(x1 * c - x2 * sn);
        dst[j + 32] = f2b_bits(x2 * c + x1 * sn);
    }
}

// ---------------- V transpose: qkv[s][4608 + kh*64 + d] -> vT[kh][d][s] ----------------
__global__ __launch_bounds__(256) void vtrans_kernel(const ushort* __restrict__ qkv, ushort* __restrict__ vT) {
    __shared__ ushort t[64][65];
    const int kh = blockIdx.x >> 5;
    const int s0 = (blockIdx.x & 31) * 64;
    const int tid = threadIdx.x;
    #pragma unroll
    for (int it = 0; it < 16; ++it) {
        int e = it * 256 + tid;
        int sl = e >> 6, d = e & 63;
        t[d][sl] = qkv[(size_t)(s0 + sl) * QKV_DIM + Q_SZ + K_SZ + kh * HD + d];
    }
    __syncthreads();
    #pragma unroll
    for (int it = 0; it < 16; ++it) {
        int e = it * 256 + tid;
        int d = e >> 6, sl = e & 63;
        vT[((size_t)kh * HD + d) * SEQ + s0 + sl] = t[d][sl];
    }
}

// ---------------- attention v5: swapped QK^T (S^T in regs), fixed-max softmax, ----------------
// cvt_pk bf16 pack + ds_write_b64 P stores, double-buffered K and V, one barrier/tile.
__global__ __launch_bounds__(256, 4) void attn_kernel(
    const ushort* __restrict__ q_ro, const ushort* __restrict__ k_ro,
    const ushort* __restrict__ vT, const float* __restrict__ sinks,
    ushort* __restrict__ attn_out)
{
    __shared__ __align__(16) ushort Kb[2][4096];
    __shared__ __align__(16) ushort Vb[2][4096];
    __shared__ __align__(16) ushort Pl[4][1024];

    const int tid = threadIdx.x;
    const int lane = tid & 63;
    const int w = tid >> 6;
    const int l15 = lane & 15;
    const int l4 = lane >> 4;

    // XCD-chunked bijective swizzle: 1024 blocks, XCD x owns wgid [x*128,(x+1)*128) = one kv-head
    int wg = blockIdx.x;
    int wgid = (wg & 7) * 128 + (wg >> 3);
    const int kh = wgid >> 7;        // 0..7
    const int qh = (wgid >> 4) & 7;  // 0..7
    const int pp = wgid & 15;        // 0..15
    const int h = kh * 8 + qh;

    const float snk = sinks[h];
    char* pbase = (char*)&Pl[w][0];

    const short oneb = (short)0x3F80;  // bf16 1.0
    const bf16x8 bones = {oneb, oneb, oneb, oneb, oneb, oneb, oneb, oneb};

    // ---- hoisted staging addresses (2 chunks/thread/array) ----
    const int i0 = tid, i1 = 256 + tid;
    const int r0 = i0 >> 3, cs0 = (i0 ^ r0) & 7;
    const int r1 = i1 >> 3, cs1 = (i1 ^ r1) & 7;
    const ushort* gK0 = k_ro + (size_t)kh * (SEQ * 64) + r0 * 64 + cs0 * 8;
    const ushort* gK1 = k_ro + (size_t)kh * (SEQ * 64) + r1 * 64 + cs1 * 8;
    const ushort* gV0 = vT + ((size_t)kh * 64 + r0) * SEQ + cs0 * 8;
    const ushort* gV1 = vT + ((size_t)kh * 64 + r1) * SEQ + cs1 * 8;
    const int ld0 = (tid & ~63) * 8, ld1 = (256 + (tid & ~63)) * 8;

    // ---- per-lane LDS byte bases ----
    const int swz = (l15 & 7) << 4;
    const int kvbase = l15 * 128 + ((l4 * 16) ^ swz);  // K/V frag reads (^ kc*64, + c/df*2048)
    const int pwbase = l15 * 128 + ((l4 * 8) ^ swz);   // P writes (^ c*32)

    auto stage = [&](int bs, int k0) {
        llds16(gK0 + k0 * 64, &Kb[bs][ld0]);
        llds16(gK1 + k0 * 64, &Kb[bs][ld1]);
        llds16(gV0 + k0,      &Vb[bs][ld0]);
        llds16(gV1 + k0,      &Vb[bs][ld1]);
    };

    for (int sidx = 0; sidx < 2; ++sidx) {
        const int qt = sidx ? (31 - pp) : pp;
        const int q0 = qt * 64;
        const int qw = q0 + w * 16;

        bf16x8 aq[2];
        #pragma unroll
        for (int kc = 0; kc < 2; ++kc)
            aq[kc] = *reinterpret_cast<const bf16x8*>(
                q_ro + ((size_t)h * SEQ + qw + l15) * HD + kc * 32 + l4 * 8);

        f32x4 o[4] = {};
        f32x4 lacc = {0.f, 0.f, 0.f, 0.f};

        const int kt0 = (qt >= 2) ? (qt - 2) : 0;
        int cur = 0;

        stage(0, kt0 * 64);
        __syncthreads();

        for (int kt = kt0; kt < SEQ / 64; ++kt) {
            const int k0 = kt * 64;
            if (kt + 1 < SEQ / 64) stage(cur ^ 1, k0 + 64);

            // ---- QK^T swapped: S^T[k][q] = K x Q ----
            f32x4 s[4];
            const f32x4 z = {0.f, 0.f, 0.f, 0.f};
            const char* kbp = (const char*)Kb[cur];
            __builtin_amdgcn_s_setprio(1);
            #pragma unroll
            for (int c = 0; c < 4; ++c) {
                bf16x8 bk0 = *reinterpret_cast<const bf16x8*>(kbp + c * 2048 + kvbase);
                s[c] = __builtin_amdgcn_mfma_f32_16x16x32_bf16(bk0, aq[0], z, 0, 0, 0);
                bf16x8 bk1 = *reinterpret_cast<const bf16x8*>(kbp + c * 2048 + (kvbase ^ 64));
                s[c] = __builtin_amdgcn_mfma_f32_16x16x32_bf16(bk1, aq[1], s[c], 0, 0, 0);
            }
            __builtin_amdgcn_s_setprio(0);

            // ---- sliding-window mask (only old keys: q - k > 128); first tile only ----
            if (k0 < qw - 113) {
                int thr = qw + l15 - 128 - k0;  // local k < thr -> masked
                #pragma unroll
                for (int c = 0; c < 4; ++c)
                    #pragma unroll
                    for (int r = 0; r < 4; ++r)
                        if (c * 16 + l4 * 4 + r < thr) s[c][r] = -1e30f;
            }

            // ---- fixed-max softmax: p = exp2(s); pack pairs; b64 store to P[q][k] ----
            #pragma unroll
            for (int c = 0; c < 4; ++c) {
                float p0 = exp2f(s[c][0]), p1 = exp2f(s[c][1]);
                float p2 = exp2f(s[c][2]), p3 = exp2f(s[c][3]);
                unsigned int pk0, pk1;
                asm("v_cvt_pk_bf16_f32 %0, %1, %2" : "=v"(pk0) : "v"(p0), "v"(p1));
                asm("v_cvt_pk_bf16_f32 %0, %1, %2" : "=v"(pk1) : "v"(p2), "v"(p3));
                uint2 pv; pv.x = pk0; pv.y = pk1;
                *reinterpret_cast<uint2*>(pbase + (pwbase ^ (c * 32))) = pv;
            }

            // ---- PV + l via ones-MFMA ----
            const char* vbp = (const char*)Vb[cur];
            __builtin_amdgcn_s_setprio(1);
            #pragma unroll
            for (int kc = 0; kc < 2; ++kc) {
                bf16x8 pa = *reinterpret_cast<const bf16x8*>(pbase + (kvbase ^ (kc * 64)));
                lacc = __builtin_amdgcn_mfma_f32_16x16x32_bf16(pa, bones, lacc, 0, 0, 0);
                #pragma unroll
                for (int df = 0; df < 4; ++df) {
                    bf16x8 bv = *reinterpret_cast<const bf16x8*>(vbp + df * 2048 + (kvbase ^ (kc * 64)));
                    o[df] = __builtin_amdgcn_mfma_f32_16x16x32_bf16(pa, bv, o[df], 0, 0, 0);
                }
            }
            __builtin_amdgcn_s_setprio(0);

            __syncthreads();  // drains vmcnt(0): next tile staged; all waves done with cur
            cur ^= 1;
        }

        // ---- epilogue: denom = sum(p) + exp(sink) ----
        {
            const float es = exp2f(snk * 1.4426950408889634f);
            float inv[4];
            #pragma unroll
            for (int r = 0; r < 4; ++r) inv[r] = 1.0f / (lacc[r] + es);
            #pragma unroll
            for (int df = 0; df < 4; ++df)
                #pragma unroll
                for (int r = 0; r < 4; ++r) {
                    int row = qw + l4 * 4 + r;
                    int col = df * 16 + l15;
                    attn_out[(size_t)row * Q_SZ + h * HD + col] = f2b_bits(o[df][r] * inv[r]);
                }
        }
    }
}

extern "C" void kernel_launch(void* const* d_in, const int* in_sizes, int n_in,
                              void* d_out, int out_size, void* d_ws, size_t ws_size,
                              hipStream_t stream) {
    const float* hidden = (const float*)d_in[0];
    const float* qkv_w  = (const float*)d_in[1];
    const float* qkv_b  = (const float*)d_in[2];
    const float* o_w    = (const float*)d_in[3];
    const float* o_b    = (const float*)d_in[4];
    const float* sinks  = (const float*)d_in[5];
    const int*   pos    = (const int*)d_in[6];
    float* out = (float*)d_out;

    char* ws = (char*)d_ws;
    size_t off = 0;
    auto alloc = [&](size_t bytes) {
        char* p = ws + off;
        off += (bytes + 255) & ~(size_t)255;
        return p;
    };
    ushort* hs_bf   = (ushort*)alloc((size_t)SEQ * HIDDEN * 2);
    ushort* wqkv_bf = (ushort*)alloc((size_t)QKV_DIM * HIDDEN * 2);
    ushort* qkv_bf  = (ushort*)alloc((size_t)SEQ * QKV_DIM * 2);
    ushort* q_ro    = (ushort*)alloc((size_t)NQ * SEQ * HD * 2);
    ushort* k_ro    = (ushort*)alloc((size_t)NKV * SEQ * HD * 2);
    ushort* vT      = (ushort*)alloc((size_t)NKV * HD * SEQ * 2);
    ushort* attn_bf = (ushort*)alloc((size_t)SEQ * Q_SZ * 2);
    ushort* wo_bf   = (ushort*)alloc((size_t)OW_NPAD * OW_K * 2);

    convert_all<<<2048, 256, 0, stream>>>(hidden, qkv_w, o_w, hs_bf, wqkv_bf, wo_bf);

    gemm_bt<1><<<(QKV_DIM / 128) * (SEQ / 128), 256, 0, stream>>>(
        hs_bf, wqkv_bf, qkv_b, qkv_bf, SEQ, QKV_DIM, HIDDEN, QKV_DIM, QKV_DIM);

    rope_kernel<<<SEQ, 256, 0, stream>>>(qkv_bf, pos, q_ro, k_ro);
    vtrans_kernel<<<NKV * 32, 256, 0, stream>>>(qkv_bf, vT);

    attn_kernel<<<1024, 256, 0, stream>>>(q_ro, k_ro, vT, sinks, attn_bf);

    gemm_bt<0><<<(OW_NPAD / 128) * (SEQ / 128), 256, 0, stream>>>(
        attn_bf, wo_bf, o_b, out, SEQ, OW_NPAD, OW_K, OW_N, OW_N);
}